// Round 1
// 526.745 us; speedup vs baseline: 1.1232x; 1.1232x over previous
//
#include <hip/hip_runtime.h>

#define N_ENT  30000
#define N_CON  29309
#define DIM    128
#define NBASIS 8
#define NREL   12
#define BATCH  256
#define LCON   50
#define SSEED  32
#define EDB    300000
#define ECON   200000
#define NTILE  938   // ceil(N_ENT/32)

#define NE4      ((N_CON * DIM) / 4)          // 937888 (exact)
#define NB_HIST  ((EDB + ECON + 255) / 256)   // 1954
#define NB_CONV  ((NE4 + 3 * (DIM * DIM / 4) + 255) / 256)
#define NB_WCOMP ((N_ENT * 32) / 256)         // 3750
#define NB_GXW   ((N_CON + 31) / 32)          // 916
#define NB_RG    ((N_ENT + 3) / 4)            // 7500
#define NB_GG    ((N_CON + 3) / 4)            // 7328
#define NB_EDB   ((N_ENT + 31) / 32)          // 938
#define NB_ECON  ((N_CON + 31) / 32)          // 916

typedef __attribute__((ext_vector_type(8)))  short bfrag8;
typedef __attribute__((ext_vector_type(16))) float facc16;

__device__ __forceinline__ unsigned short f2bf(float f) {
    unsigned int u = __float_as_uint(f);
    u += 0x7FFFu + ((u >> 16) & 1u);
    return (unsigned short)(u >> 16);
}
__device__ __forceinline__ float bf2f(unsigned int h) {
    return __uint_as_float(h << 16);
}

// ============================ dispatch 1: hist (with ordinals) + bf16 conversions
__global__ __launch_bounds__(256) void prep_kernel(const int* __restrict__ db_dst,
                                                   const int* __restrict__ con_dst,
                                                   const float* __restrict__ emb,
                                                   const float* __restrict__ W,
                                                   const float* __restrict__ A_db,
                                                   const float* __restrict__ A_c,
                                                   int* __restrict__ cnt_e, int* __restrict__ cnt_c,
                                                   int* __restrict__ ord_db, int* __restrict__ ord_con,
                                                   unsigned short* __restrict__ emb_h,
                                                   unsigned short* __restrict__ Wt_h,
                                                   unsigned short* __restrict__ At_db_h,
                                                   unsigned short* __restrict__ At_c_h) {
    int t = threadIdx.x, bb = blockIdx.x;
    if (bb < NB_HIST) {
        int e = bb * 256 + t;
        if (e < EDB) {
            ord_db[e] = atomicAdd(cnt_e + db_dst[e], 1);
        } else if (e < EDB + ECON) {
            int ee = e - EDB;
            ord_con[ee] = atomicAdd(cnt_c + con_dst[ee], 1);
        }
    } else {
        int i = (bb - NB_HIST) * 256 + t;
        if (i < NE4) {
            float4 v = ((const float4*)emb)[i];
            unsigned int p0 = (unsigned int)f2bf(v.x) | ((unsigned int)f2bf(v.y) << 16);
            unsigned int p1 = (unsigned int)f2bf(v.z) | ((unsigned int)f2bf(v.w) << 16);
            *(uint2*)(emb_h + (size_t)i * 4) = make_uint2(p0, p1);
        } else {
            int j = i - NE4;
            if (j < 3 * (DIM * DIM) / 4) {
                int sel = j >> 12;             // DIM*DIM/4 = 4096 = 1<<12
                int jj = j & 4095;
                const float* S = (sel == 0) ? W : ((sel == 1) ? A_db : A_c);
                unsigned short* Dst = (sel == 0) ? Wt_h : ((sel == 1) ? At_db_h : At_c_h);
                int o = jj * 4;
                int n = o >> 7, k0 = o & 127;
                unsigned int p0 = (unsigned int)f2bf(S[(k0 + 0) * DIM + n]) |
                                  ((unsigned int)f2bf(S[(k0 + 1) * DIM + n]) << 16);
                unsigned int p1 = (unsigned int)f2bf(S[(k0 + 2) * DIM + n]) |
                                  ((unsigned int)f2bf(S[(k0 + 3) * DIM + n]) << 16);
                *(uint2*)(Dst + n * DIM + k0) = make_uint2(p0, p1);
            }
        }
    }
}

// ============================ dispatch 2: two exclusive scans (+dinv)
__device__ void scan_block(const int* __restrict__ cnt, int n, int* __restrict__ rowptr) {
    __shared__ int part[1024];
    int t = threadIdx.x;
    int per = (n + 1023) / 1024;
    int s0 = t * per;
    int sum = 0;
    for (int i = 0; i < per; ++i) {
        int idx = s0 + i;
        if (idx < n) sum += cnt[idx];
    }
    part[t] = sum;
    __syncthreads();
    for (int off = 1; off < 1024; off <<= 1) {
        int v = (t >= off) ? part[t - off] : 0;
        __syncthreads();
        part[t] += v;
        __syncthreads();
    }
    int run = part[t] - sum;
    for (int i = 0; i < per; ++i) {
        int idx = s0 + i;
        if (idx < n) {
            rowptr[idx] = run;
            run += cnt[idx];
        }
    }
    if (t == 1023) rowptr[n] = part[1023];
}

__global__ __launch_bounds__(1024) void scan2_kernel(const int* __restrict__ cnt_e,
                                                     const int* __restrict__ cnt_c,
                                                     int* __restrict__ rowptr_e,
                                                     int* __restrict__ rowptr_c,
                                                     float* __restrict__ dinv) {
    if (blockIdx.x == 0) {
        scan_block(cnt_e, N_ENT, rowptr_e);
    } else {
        scan_block(cnt_c, N_CON, rowptr_c);
        for (int i = threadIdx.x; i < N_CON; i += 1024)
            dinv[i] = rsqrtf((float)(cnt_c[i] + 1));
    }
}

// ============================ dispatch 3: scatter + wcomp + gcn_xw MFMA (block-range fused)
__global__ __launch_bounds__(256) void mid_kernel(const int* __restrict__ db_eidx,
                                                  const int* __restrict__ db_etype,
                                                  const int* __restrict__ con_eidx,
                                                  const int* __restrict__ ord_db,
                                                  const int* __restrict__ ord_con,
                                                  const int* __restrict__ rowptr_e,
                                                  const int* __restrict__ rowptr_c,
                                                  int* __restrict__ elist_e,
                                                  int* __restrict__ elist_c,
                                                  const float* __restrict__ basis,
                                                  const float* __restrict__ comp,
                                                  unsigned short* __restrict__ w_h,
                                                  const unsigned short* __restrict__ emb_h,
                                                  const unsigned short* __restrict__ Wt_h,
                                                  unsigned short* __restrict__ xw_h,
                                                  int use_w) {
    __shared__ float sc[NREL * NBASIS];
    int t = threadIdx.x, bb = blockIdx.x;
    if (bb < NB_HIST) {
        // ---- scatter (pure writes, ordinals precomputed)
        int e = bb * 256 + t;
        if (e < EDB) {
            int dst = db_eidx[EDB + e];
            elist_e[rowptr_e[dst] + ord_db[e]] = db_eidx[e] | (db_etype[e] << 18);
        } else if (e < EDB + ECON) {
            int ee = e - EDB;
            int dst = con_eidx[ECON + ee];
            elist_c[rowptr_c[dst] + ord_con[ee]] = con_eidx[ee];
        }
        return;
    }
    if (bb < NB_HIST + NB_WCOMP) {
        // ---- w_h[r,n,:] = bf16(sum_b comp[r,b]*basis[b,n,:])
        if (!use_w) return;
        if (t < NREL * NBASIS) sc[t] = comp[t];
        __syncthreads();
        int i = (bb - NB_HIST) * 256 + t;
        int n = i >> 5, d4 = i & 31;
        float4 bv[NBASIS];
#pragma unroll
        for (int b = 0; b < NBASIS; ++b)
            bv[b] = ((const float4*)(basis + ((size_t)b * N_ENT + n) * DIM))[d4];
#pragma unroll
        for (int r = 0; r < NREL; ++r) {
            float4 acc = make_float4(0.f, 0.f, 0.f, 0.f);
#pragma unroll
            for (int b = 0; b < NBASIS; ++b) {
                float c = sc[r * NBASIS + b];
                acc.x += c * bv[b].x; acc.y += c * bv[b].y;
                acc.z += c * bv[b].z; acc.w += c * bv[b].w;
            }
            unsigned int p0 = (unsigned int)f2bf(acc.x) | ((unsigned int)f2bf(acc.y) << 16);
            unsigned int p1 = (unsigned int)f2bf(acc.z) | ((unsigned int)f2bf(acc.w) << 16);
            *(uint2*)(w_h + ((size_t)r * N_ENT + n) * DIM + d4 * 4) = make_uint2(p0, p1);
        }
        return;
    }
    // ---- xw_h = bf16(emb @ W) via MFMA
    {
        int gb = bb - NB_HIST - NB_WCOMP;
        int wave = t >> 6, lane = t & 63;
        int m0 = gb * 32;
        int n0 = wave * 32;
        int am = lane & 31, ak = (lane >> 5) * 8;
        int mrow = m0 + am;
        bool mv = mrow < N_CON;
        const unsigned short* Ar = emb_h + (size_t)mrow * DIM + ak;
        const unsigned short* Br = Wt_h + (size_t)(n0 + am) * DIM + ak;
        facc16 acc;
#pragma unroll
        for (int r = 0; r < 16; ++r) acc[r] = 0.f;
#pragma unroll
        for (int s = 0; s < 8; ++s) {
            bfrag8 a;
#pragma unroll
            for (int j = 0; j < 8; ++j) a[j] = 0;
            if (mv) a = *(const bfrag8*)(Ar + s * 16);
            bfrag8 b = *(const bfrag8*)(Br + s * 16);
            acc = __builtin_amdgcn_mfma_f32_32x32x16_bf16(a, b, acc, 0, 0, 0);
        }
        int col = lane & 31;
        int g4 = (lane >> 5) * 4;
#pragma unroll
        for (int r = 0; r < 16; ++r) {
            int m = m0 + (r & 3) + ((r >> 2) << 3) + g4;
            if (m < N_CON) xw_h[(size_t)m * DIM + n0 + col] = f2bf(acc[r]);
        }
    }
}

// ============================ dispatch 4: both graph gathers (block-range fused)
__global__ __launch_bounds__(256) void gathers_kernel(const int* __restrict__ rowptr_e,
                                                      const int* __restrict__ elist_e,
                                                      const unsigned short* __restrict__ w_h,
                                                      const float* __restrict__ root,
                                                      const float* __restrict__ bias,
                                                      unsigned short* __restrict__ dbf_h,
                                                      const int* __restrict__ rowptr_c,
                                                      const int* __restrict__ elist_c,
                                                      const float* __restrict__ dinv,
                                                      const unsigned short* __restrict__ xw_h,
                                                      const float* __restrict__ gcn_b,
                                                      unsigned short* __restrict__ conf_h) {
    int bb = blockIdx.x;
    int lane = threadIdx.x & 63;
    if (bb < NB_RG) {
        int wid = bb * 4 + (threadIdx.x >> 6);
        if (wid >= N_ENT) return;
        int beg = rowptr_e[wid], end = rowptr_e[wid + 1];
        float a0 = 0.f, a1 = 0.f;
        int p = beg;
        for (; p + 1 < end; p += 2) {
            int v0 = elist_e[p], v1 = elist_e[p + 1];
            unsigned int k0 = *(const unsigned int*)(w_h + ((size_t)(v0 >> 18) * N_ENT + (v0 & 0x3FFFF)) * DIM + lane * 2);
            unsigned int k1 = *(const unsigned int*)(w_h + ((size_t)(v1 >> 18) * N_ENT + (v1 & 0x3FFFF)) * DIM + lane * 2);
            a0 += bf2f(k0 & 0xFFFF) + bf2f(k1 & 0xFFFF);
            a1 += bf2f(k0 >> 16)    + bf2f(k1 >> 16);
        }
        if (p < end) {
            int v = elist_e[p];
            unsigned int k = *(const unsigned int*)(w_h + ((size_t)(v >> 18) * N_ENT + (v & 0x3FFFF)) * DIM + lane * 2);
            a0 += bf2f(k & 0xFFFF);
            a1 += bf2f(k >> 16);
        }
        float inv = 1.f / fmaxf((float)(end - beg), 1.f);
        size_t base = (size_t)wid * DIM + lane * 2;
        float f0 = a0 * inv + root[base]     + bias[lane * 2];
        float f1 = a1 * inv + root[base + 1] + bias[lane * 2 + 1];
        *(unsigned int*)(dbf_h + base) = (unsigned int)f2bf(f0) | ((unsigned int)f2bf(f1) << 16);
    } else {
        int wid = (bb - NB_RG) * 4 + (threadIdx.x >> 6);
        if (wid >= N_CON) return;
        int beg = rowptr_c[wid], end = rowptr_c[wid + 1];
        float a0 = 0.f, a1 = 0.f;
        int p = beg;
        for (; p + 1 < end; p += 2) {
            int s0 = elist_c[p], s1 = elist_c[p + 1];
            float n0 = dinv[s0], n1 = dinv[s1];
            unsigned int k0 = *(const unsigned int*)(xw_h + (size_t)s0 * DIM + lane * 2);
            unsigned int k1 = *(const unsigned int*)(xw_h + (size_t)s1 * DIM + lane * 2);
            a0 += n0 * bf2f(k0 & 0xFFFF) + n1 * bf2f(k1 & 0xFFFF);
            a1 += n0 * bf2f(k0 >> 16)    + n1 * bf2f(k1 >> 16);
        }
        if (p < end) {
            int s = elist_c[p];
            float nm = dinv[s];
            unsigned int k = *(const unsigned int*)(xw_h + (size_t)s * DIM + lane * 2);
            a0 += nm * bf2f(k & 0xFFFF);
            a1 += nm * bf2f(k >> 16);
        }
        float dv = dinv[wid];
        unsigned int ks = *(const unsigned int*)(xw_h + (size_t)wid * DIM + lane * 2);
        size_t base = (size_t)wid * DIM + lane * 2;
        float f0 = dv * a0 + dv * dv * bf2f(ks & 0xFFFF) + gcn_b[lane * 2];
        float f1 = dv * a1 + dv * dv * bf2f(ks >> 16)    + gcn_b[lane * 2 + 1];
        *(unsigned int*)(conf_h + base) = (unsigned int)f2bf(f0) | ((unsigned int)f2bf(f1) << 16);
    }
}

// fallback when ws too small for w_h: RGCN gather straight from fp32 basis
__global__ __launch_bounds__(256) void rgcn_gather_basis(const int* __restrict__ rowptr,
                                                         const int* __restrict__ elist,
                                                         const float* __restrict__ basis,
                                                         const float* __restrict__ comp,
                                                         const float* __restrict__ root,
                                                         const float* __restrict__ bias,
                                                         unsigned short* __restrict__ dbf_h) {
    int wid  = blockIdx.x * 4 + (threadIdx.x >> 6);
    int lane = threadIdx.x & 63;
    if (wid >= N_ENT) return;
    int beg = rowptr[wid], end = rowptr[wid + 1];
    float a0 = 0.f, a1 = 0.f;
    for (int p = beg; p < end; ++p) {
        int v = elist[p];
        int src = v & 0x3FFFF, ty = v >> 18;
        const float* c = comp + ty * NBASIS;
#pragma unroll
        for (int b = 0; b < NBASIS; ++b) {
            const float* bp = basis + ((size_t)b * N_ENT + src) * DIM;
            a0 += c[b] * bp[lane * 2];
            a1 += c[b] * bp[lane * 2 + 1];
        }
    }
    float inv = 1.f / fmaxf((float)(end - beg), 1.f);
    size_t base = (size_t)wid * DIM + lane * 2;
    float f0 = a0 * inv + root[base]     + bias[lane * 2];
    float f1 = a1 * inv + root[base + 1] + bias[lane * 2 + 1];
    *(unsigned int*)(dbf_h + base) = (unsigned int)f2bf(f0) | ((unsigned int)f2bf(f1) << 16);
}

// ============================ dispatch 5: attention scores for ALL rows via MFMA
// e[n] = sum_d v[d] * tanh( (feats[n,:] @ A)[d] ), computed for every entity/concept.
// score(gather(rows)) == gather(score(rows)) since e is a per-row function.
__global__ __launch_bounds__(256) void escore_kernel(const unsigned short* __restrict__ dbf_h,
                                                     const unsigned short* __restrict__ conf_h,
                                                     const unsigned short* __restrict__ At_db_h,
                                                     const float* __restrict__ v_db,
                                                     const unsigned short* __restrict__ At_c_h,
                                                     const float* __restrict__ v_c,
                                                     float* __restrict__ e_db,
                                                     float* __restrict__ e_con) {
    __shared__ float part[4][32];
    int t = threadIdx.x, bb = blockIdx.x;
    int wave = t >> 6, lane = t & 63;
    const unsigned short* feats;
    const unsigned short* At;
    const float* v;
    float* eo;
    int m0, nrow;
    if (bb < NB_EDB) {
        feats = dbf_h;  At = At_db_h; v = v_db; eo = e_db;  m0 = bb * 32;             nrow = N_ENT;
    } else {
        feats = conf_h; At = At_c_h;  v = v_c;  eo = e_con; m0 = (bb - NB_EDB) * 32;  nrow = N_CON;
    }
    int n0 = wave * 32;                 // 4 waves cover all 128 output dims
    int am = lane & 31, ak = (lane >> 5) * 8;
    int mrow = m0 + am;
    bool mv = mrow < nrow;
    const unsigned short* Ar = feats + (size_t)mrow * DIM + ak;
    const unsigned short* Br = At + (size_t)(n0 + am) * DIM + ak;
    facc16 acc;
#pragma unroll
    for (int r = 0; r < 16; ++r) acc[r] = 0.f;
#pragma unroll
    for (int s = 0; s < 8; ++s) {
        bfrag8 a;
#pragma unroll
        for (int j = 0; j < 8; ++j) a[j] = 0;
        if (mv) a = *(const bfrag8*)(Ar + s * 16);
        bfrag8 b = *(const bfrag8*)(Br + s * 16);
        acc = __builtin_amdgcn_mfma_f32_32x32x16_bf16(a, b, acc, 0, 0, 0);
    }
    int col = lane & 31, g = lane >> 5;
    float vn = v[n0 + col];
    // each acc[r] is one (row, col) element; reduce tanh(x)*v over the 32 cols (lanes)
#pragma unroll
    for (int r = 0; r < 16; ++r) {
        float x = tanhf(acc[r]) * vn;
#pragma unroll
        for (int off = 16; off >= 1; off >>= 1) x += __shfl_xor(x, off, 32);
        if (col == 0) {
            int row = (r & 3) + ((r >> 2) << 3) + (g << 2);
            part[wave][row] = x;
        }
    }
    __syncthreads();
    if (t < 32) {
        int m = m0 + t;
        if (m < nrow)
            eo[m] = part[0][t] + part[1][t] + part[2][t] + part[3][t];
    }
}

// ============================ dispatch 6: softmax + weighted sums + gated fusion per sample
__global__ __launch_bounds__(256) void attn_fusion_kernel(const unsigned short* __restrict__ dbf_h,
                                                          const unsigned short* __restrict__ conf_h,
                                                          const float* __restrict__ e_db,
                                                          const float* __restrict__ e_con,
                                                          const int* __restrict__ seed_pad,
                                                          const int* __restrict__ seed_lens,
                                                          const int* __restrict__ concept_mask,
                                                          const float* __restrict__ Wu, const float* __restrict__ bu,
                                                          const float* __restrict__ gw, const float* __restrict__ gb,
                                                          const float* __restrict__ Wi, const float* __restrict__ bi,
                                                          unsigned short* __restrict__ uemb_h,
                                                          unsigned short* __restrict__ cone_h,
                                                          float* __restrict__ maskv) {
    __shared__ int srow[SSEED];
    __shared__ int crow[LCON];
    __shared__ float a_db[SSEED], a_con[LCON];
    __shared__ float du[DIM], cu[DIM], red[DIM];
    int b = blockIdx.x, t = threadIdx.x;
    int wave = t >> 6, lane = t & 63;
    int len = seed_lens[b];
    if (wave == 0) {
        // db softmax over S=32 (lanes 0..31)
        float e = -1e30f;
        if (lane < SSEED) {
            int rv = seed_pad[b * SSEED + lane];
            srow[lane] = rv;
            if (lane < len) e = e_db[rv];
        }
        float m = e;
#pragma unroll
        for (int off = 16; off >= 1; off >>= 1) m = fmaxf(m, __shfl_xor(m, off, 32));
        float p = (lane < SSEED) ? __expf(e - m) : 0.f;
        float s = p;
#pragma unroll
        for (int off = 16; off >= 1; off >>= 1) s += __shfl_xor(s, off, 32);
        if (lane < SSEED) a_db[lane] = p / s;
    } else if (wave == 1) {
        // con softmax over LC=50 (lanes 0..49)
        float e = -1e30f;
        if (lane < LCON) {
            int rv = concept_mask[b * LCON + lane];
            crow[lane] = rv;
            if (rv != 0) e = e_con[rv];
        }
        float m = e;
#pragma unroll
        for (int off = 32; off >= 1; off >>= 1) m = fmaxf(m, __shfl_xor(m, off, 64));
        float p = (lane < LCON) ? __expf(e - m) : 0.f;
        float s = p;
#pragma unroll
        for (int off = 32; off >= 1; off >>= 1) s += __shfl_xor(s, off, 64);
        if (lane < LCON) a_con[lane] = p / s;
    }
    __syncthreads();
    // weighted row sums: threads 0..127 -> du, 128..255 -> cu
    if (t < DIM) {
        float acc = 0.f;
#pragma unroll
        for (int s = 0; s < SSEED; ++s)
            acc += a_db[s] * bf2f((unsigned int)dbf_h[(size_t)srow[s] * DIM + t]);
        du[t] = (len > 0) ? acc : 0.f;
    } else {
        int d = t - DIM;
        float acc = 0.f;
#pragma unroll
        for (int s = 0; s < LCON; ++s)
            acc += a_con[s] * bf2f((unsigned int)conf_h[(size_t)crow[s] * DIM + d]);
        cu[d] = acc;
    }
    __syncthreads();
    // fusion
    if (t < DIM) {
        float u = bu[t];
        const float* wr = Wu + t * 2 * DIM;
        for (int k = 0; k < DIM; ++k) u += cu[k] * wr[k];
        for (int k = 0; k < DIM; ++k) u += du[k] * wr[DIM + k];
        red[t] = u * gw[t];
    }
    __syncthreads();
    for (int s2 = 64; s2 > 0; s2 >>= 1) {
        if (t < s2) red[t] += red[t + s2];
        __syncthreads();
    }
    if (t < DIM) {
        float gate = 1.f / (1.f + __expf(-(red[0] + gb[0])));
        uemb_h[b * DIM + t] = f2bf(gate * du[t] + (1.f - gate) * cu[t]);
        float ce = bi[t];
        const float* wi = Wi + t * DIM;
        for (int k = 0; k < DIM; ++k) ce += cu[k] * wi[k];
        cone_h[b * DIM + t] = f2bf(ce);
    }
    if (t == 0) maskv[b] = (len > 0) ? 1.f : 0.f;
}

// ============================ dispatch 7: fused scoring GEMMs (MFMA) + CE/ssq partials
__global__ __launch_bounds__(256) void score_mfma(const unsigned short* __restrict__ dbf_h,
                                                  const unsigned short* __restrict__ uemb_h,
                                                  const unsigned short* __restrict__ cone_h,
                                                  const float* __restrict__ en_b,
                                                  const float* __restrict__ info_b,
                                                  const float* __restrict__ db_vec,
                                                  float* __restrict__ escore,
                                                  float* __restrict__ partM,
                                                  float* __restrict__ partS,
                                                  float* __restrict__ partQ) {
    int wave = threadIdx.x >> 6, lane = threadIdx.x & 63;
    int nt = blockIdx.x * 4 + wave;
    if (nt >= NTILE) return;
    int b0 = blockIdx.y * 32;
    int n0 = nt * 32;
    int am = lane & 31, ak = (lane >> 5) * 8;
    int nb = n0 + am;
    bool bvalid = nb < N_ENT;
    const unsigned short* Au = uemb_h + (size_t)(b0 + am) * DIM + ak;
    const unsigned short* Ac = cone_h + (size_t)(b0 + am) * DIM + ak;
    const unsigned short* Bp = dbf_h + (size_t)nb * DIM + ak;
    facc16 accE, accD;
#pragma unroll
    for (int r = 0; r < 16; ++r) { accE[r] = 0.f; accD[r] = 0.f; }
#pragma unroll
    for (int s = 0; s < 8; ++s) {
        bfrag8 au = *(const bfrag8*)(Au + s * 16);
        bfrag8 ac = *(const bfrag8*)(Ac + s * 16);
        bfrag8 bb;
#pragma unroll
        for (int j = 0; j < 8; ++j) bb[j] = 0;
        if (bvalid) bb = *(const bfrag8*)(Bp + s * 16);
        accE = __builtin_amdgcn_mfma_f32_32x32x16_bf16(au, bb, accE, 0, 0, 0);
        accD = __builtin_amdgcn_mfma_f32_32x32x16_bf16(ac, bb, accD, 0, 0, 0);
    }
    int col = lane & 31;
    int n = n0 + col;
    bool nv = n < N_ENT;
    float enb = nv ? en_b[n] : 0.f;
    float inb = nv ? info_b[n] : 0.f;
    int g4 = (lane >> 5) * 4;
#pragma unroll
    for (int r = 0; r < 16; ++r) {
        int b = b0 + (r & 3) + ((r >> 2) << 3) + g4;
        float e = accE[r] + enb;
        if (nv) escore[(size_t)b * N_ENT + n] = e;
        float ev = nv ? e : -1e30f;
        float mx = ev;
#pragma unroll
        for (int off = 16; off >= 1; off >>= 1) mx = fmaxf(mx, __shfl_xor(mx, off, 64));
        float ex = nv ? __expf(e - mx) : 0.f;
        float sm = ex;
#pragma unroll
        for (int off = 16; off >= 1; off >>= 1) sm += __shfl_xor(sm, off, 64);
        float d = nv ? (accD[r] + inb - db_vec[(size_t)b * N_ENT + n]) : 0.f;
        float q = d * d;
#pragma unroll
        for (int off = 16; off >= 1; off >>= 1) q += __shfl_xor(q, off, 64);
        if (col == 0) {
            partM[(size_t)b * NTILE + nt] = mx;
            partS[(size_t)b * NTILE + nt] = sm;
            partQ[(size_t)b * NTILE + nt] = q;
        }
    }
}

// ============================ dispatch 8: CE finalize from partials
__global__ __launch_bounds__(256) void ce_final(const float* __restrict__ partM,
                                                const float* __restrict__ partS,
                                                const float* __restrict__ partQ,
                                                const float* __restrict__ escore,
                                                const int* __restrict__ labels,
                                                const float* __restrict__ rec,
                                                float* __restrict__ rloss,
                                                float* __restrict__ ssqv) {
    __shared__ float red[256], red2[256];
    int b = blockIdx.x, t = threadIdx.x;
    const float* pm = partM + (size_t)b * NTILE;
    const float* ps = partS + (size_t)b * NTILE;
    const float* pq = partQ + (size_t)b * NTILE;
    float mx = -1e30f;
    for (int i = t; i < NTILE; i += 256) mx = fmaxf(mx, pm[i]);
    red[t] = mx;
    __syncthreads();
    for (int s2 = 128; s2 > 0; s2 >>= 1) {
        if (t < s2) red[t] = fmaxf(red[t], red[t + s2]);
        __syncthreads();
    }
    float M = red[0];
    __syncthreads();
    float s = 0.f, q = 0.f;
    for (int i = t; i < NTILE; i += 256) {
        s += ps[i] * __expf(pm[i] - M);
        q += pq[i];
    }
    red[t] = s; red2[t] = q;
    __syncthreads();
    for (int s2 = 128; s2 > 0; s2 >>= 1) {
        if (t < s2) { red[t] += red[t + s2]; red2[t] += red2[t + s2]; }
        __syncthreads();
    }
    if (t == 0) {
        float lse = M + logf(red[0]);
        float ce  = -(escore[(size_t)b * N_ENT + labels[b]] - lse);
        rloss[b]  = ce * rec[b];
        ssqv[b]   = red2[0];
    }
}

// ============================ dispatch 9: final scalar reduction
__global__ __launch_bounds__(256) void final_kernel(const float* __restrict__ rloss,
                                                    const float* __restrict__ sumsq,
                                                    const float* __restrict__ maskv,
                                                    float* __restrict__ out) {
    __shared__ float r1[256], r2[256];
    int t = threadIdx.x;
    r1[t] = rloss[t];
    r2[t] = sumsq[t] * maskv[t];
    __syncthreads();
    for (int s2 = 128; s2 > 0; s2 >>= 1) {
        if (t < s2) { r1[t] += r1[t + s2]; r2[t] += r2[t + s2]; }
        __syncthreads();
    }
    if (t == 0) {
        float rec_loss = r1[0];
        float info = r2[0] / (float)BATCH;
        out[0] = rec_loss + 0.025f * info;
        out[1 + (size_t)BATCH * N_ENT] = rec_loss;
    }
}

// ============================ launch
extern "C" void kernel_launch(void* const* d_in, const int* in_sizes, int n_in,
                              void* d_out, int out_size, void* d_ws, size_t ws_size,
                              hipStream_t stream) {
    (void)in_sizes; (void)n_in; (void)out_size;
    const int*   concept_mask  = (const int*)d_in[0];
    const int*   seed_pad      = (const int*)d_in[1];
    const int*   seed_lens     = (const int*)d_in[2];
    const int*   db_eidx       = (const int*)d_in[3];
    const int*   db_etype      = (const int*)d_in[4];
    const int*   con_eidx      = (const int*)d_in[5];
    const float* db_vec        = (const float*)d_in[6];
    const int*   labels        = (const int*)d_in[7];
    const float* rec           = (const float*)d_in[8];
    const float* concept_emb   = (const float*)d_in[9];
    const float* basis         = (const float*)d_in[10];
    const float* comp          = (const float*)d_in[11];
    const float* rgcn_root     = (const float*)d_in[12];
    const float* rgcn_bias     = (const float*)d_in[13];
    const float* gcn_w         = (const float*)d_in[14];
    const float* gcn_b         = (const float*)d_in[15];
    const float* attn_a        = (const float*)d_in[16];
    const float* attn_b        = (const float*)d_in[17];
    const float* attn_a_db     = (const float*)d_in[18];
    const float* attn_b_db     = (const float*)d_in[19];
    const float* user_norm_w   = (const float*)d_in[20];
    const float* user_norm_b   = (const float*)d_in[21];
    const float* gate_norm_w   = (const float*)d_in[22];
    const float* gate_norm_b   = (const float*)d_in[23];
    const float* info_con_w    = (const float*)d_in[24];
    const float* info_con_b    = (const float*)d_in[25];
    const float* info_out_db_b = (const float*)d_in[26];
    const float* output_en_b   = (const float*)d_in[27];

    float* ws = (float*)d_ws;
    size_t off = 0;
    auto alloc = [&](size_t n) { float* p = ws + off; off += (n + 255) & ~(size_t)255; return p; };
    float* dinv   = alloc(N_CON);
    float* maskv  = alloc(BATCH);
    float* rls    = alloc(BATCH);
    float* ssqv   = alloc(BATCH);
    float* partM  = alloc((size_t)BATCH * NTILE);
    float* partS  = alloc((size_t)BATCH * NTILE);
    float* partQ  = alloc((size_t)BATCH * NTILE);
    int* cnt_e    = (int*)alloc(N_ENT + N_CON);     // contiguous for one memset
    int* cnt_c    = cnt_e + N_ENT;
    int* rowptr_e = (int*)alloc(N_ENT + 1);
    int* rowptr_c = (int*)alloc(N_CON + 1);
    int* ord_db   = (int*)alloc(EDB);
    int* ord_con  = (int*)alloc(ECON);
    int* elist_e  = (int*)alloc(EDB);
    int* elist_c  = (int*)alloc(ECON);
    unsigned short* dbf_h  = (unsigned short*)alloc((size_t)N_ENT * DIM / 2);
    unsigned short* conf_h = (unsigned short*)alloc((size_t)N_CON * DIM / 2 + 128);
    unsigned short* xw_h   = (unsigned short*)alloc((size_t)N_CON * DIM / 2 + 128);
    unsigned short* emb_h  = (unsigned short*)alloc((size_t)N_CON * DIM / 2 + 128);
    unsigned short* Wt_h   = (unsigned short*)alloc(DIM * DIM / 2);
    unsigned short* uemb_h = (unsigned short*)alloc(BATCH * DIM / 2);
    unsigned short* cone_h = (unsigned short*)alloc(BATCH * DIM / 2);
    float* e_db   = alloc(N_ENT);
    float* e_con  = alloc(N_CON);
    unsigned short* At_db_h = (unsigned short*)alloc(DIM * DIM / 2);
    unsigned short* At_c_h  = (unsigned short*)alloc(DIM * DIM / 2);
    size_t w_elems = ((size_t)NREL * N_ENT * DIM) / 2;   // bf16 in float-units
    int use_w = (off + w_elems) * sizeof(float) <= ws_size;
    unsigned short* w_h = (unsigned short*)(ws + off);

    float* out    = (float*)d_out;
    float* escore = out + 1;

    (void)hipMemsetAsync(cnt_e, 0, (N_ENT + N_CON) * sizeof(int), stream);

    prep_kernel<<<NB_HIST + NB_CONV, 256, 0, stream>>>(db_eidx + EDB, con_eidx + ECON,
                                                       concept_emb, gcn_w, attn_a_db, attn_a,
                                                       cnt_e, cnt_c, ord_db, ord_con, emb_h, Wt_h,
                                                       At_db_h, At_c_h);
    scan2_kernel<<<2, 1024, 0, stream>>>(cnt_e, cnt_c, rowptr_e, rowptr_c, dinv);
    mid_kernel<<<NB_HIST + NB_WCOMP + NB_GXW, 256, 0, stream>>>(db_eidx, db_etype, con_eidx,
                                                                ord_db, ord_con, rowptr_e, rowptr_c,
                                                                elist_e, elist_c, basis, comp, w_h,
                                                                emb_h, Wt_h, xw_h, use_w);
    gathers_kernel<<<NB_RG + NB_GG, 256, 0, stream>>>(rowptr_e, elist_e, w_h, rgcn_root, rgcn_bias,
                                                      dbf_h, rowptr_c, elist_c, dinv, xw_h, gcn_b, conf_h);
    if (!use_w) {
        rgcn_gather_basis<<<NB_RG, 256, 0, stream>>>(rowptr_e, elist_e, basis, comp,
                                                     rgcn_root, rgcn_bias, dbf_h);
    }
    escore_kernel<<<NB_EDB + NB_ECON, 256, 0, stream>>>(dbf_h, conf_h, At_db_h, attn_b_db,
                                                        At_c_h, attn_b, e_db, e_con);
    attn_fusion_kernel<<<BATCH, 256, 0, stream>>>(dbf_h, conf_h, e_db, e_con,
                                                  seed_pad, seed_lens, concept_mask,
                                                  user_norm_w, user_norm_b, gate_norm_w, gate_norm_b,
                                                  info_con_w, info_con_b, uemb_h, cone_h, maskv);
    dim3 sg((NTILE + 3) / 4, BATCH / 32);
    score_mfma<<<sg, 256, 0, stream>>>(dbf_h, uemb_h, cone_h, output_en_b, info_out_db_b, db_vec,
                                       escore, partM, partS, partQ);
    ce_final<<<BATCH, 256, 0, stream>>>(partM, partS, partQ, escore, labels, rec, rls, ssqv);
    final_kernel<<<1, 256, 0, stream>>>(rls, ssqv, maskv, out);
}

// Round 2
// 517.518 us; speedup vs baseline: 1.1433x; 1.0178x over previous
//
#include <hip/hip_runtime.h>

#define N_ENT  30000
#define N_CON  29309
#define DIM    128
#define NBASIS 8
#define NREL   12
#define BATCH  256
#define LCON   50
#define SSEED  32
#define EDB    300000
#define ECON   200000
#define NTILE  938   // ceil(N_ENT/32)

#define NE4      ((N_CON * DIM) / 4)          // 937888 (exact)
#define NB_HIST  ((EDB + ECON + 255) / 256)   // 1954
#define NB_CONV  ((NE4 + 3 * (DIM * DIM / 4) + 255) / 256)
#define NB_WCOMP ((N_ENT * 32) / 256)         // 3750
#define NB_XW    ((N_CON + 127) / 128)        // 229 (1024-thread blocks, 128 rows each)
#define NB_RG    ((N_ENT + 3) / 4)            // 7500
#define NB_GG    ((N_CON + 3) / 4)            // 7328
#define NB_EDB   ((N_ENT + 31) / 32)          // 938
#define NB_ECON  ((N_CON + 31) / 32)          // 916

typedef __attribute__((ext_vector_type(8)))  short bfrag8;
typedef __attribute__((ext_vector_type(16))) float facc16;

__device__ __forceinline__ unsigned short f2bf(float f) {
    unsigned int u = __float_as_uint(f);
    u += 0x7FFFu + ((u >> 16) & 1u);
    return (unsigned short)(u >> 16);
}
__device__ __forceinline__ float bf2f(unsigned int h) {
    return __uint_as_float(h << 16);
}

// ============================ dispatch 1: hist + bf16 conversions + wcomp (all independent work)
__global__ __launch_bounds__(256) void prep_kernel(const int* __restrict__ db_dst,
                                                   const int* __restrict__ con_dst,
                                                   const float* __restrict__ emb,
                                                   const float* __restrict__ W,
                                                   const float* __restrict__ A_db,
                                                   const float* __restrict__ A_c,
                                                   const float* __restrict__ basis,
                                                   const float* __restrict__ comp,
                                                   int* __restrict__ cnt_e, int* __restrict__ cnt_c,
                                                   int* __restrict__ ord_db, int* __restrict__ ord_con,
                                                   unsigned short* __restrict__ emb_h,
                                                   unsigned short* __restrict__ Wt_h,
                                                   unsigned short* __restrict__ At_db_h,
                                                   unsigned short* __restrict__ At_c_h,
                                                   unsigned short* __restrict__ w_h,
                                                   int use_w) {
    __shared__ float sc[NREL * NBASIS];
    int t = threadIdx.x, bb = blockIdx.x;
    if (bb < NB_HIST) {
        int e = bb * 256 + t;
        if (e < EDB) {
            ord_db[e] = atomicAdd(cnt_e + db_dst[e], 1);
        } else if (e < EDB + ECON) {
            int ee = e - EDB;
            ord_con[ee] = atomicAdd(cnt_c + con_dst[ee], 1);
        }
        return;
    }
    if (bb < NB_HIST + NB_CONV) {
        int i = (bb - NB_HIST) * 256 + t;
        if (i < NE4) {
            float4 v = ((const float4*)emb)[i];
            unsigned int p0 = (unsigned int)f2bf(v.x) | ((unsigned int)f2bf(v.y) << 16);
            unsigned int p1 = (unsigned int)f2bf(v.z) | ((unsigned int)f2bf(v.w) << 16);
            *(uint2*)(emb_h + (size_t)i * 4) = make_uint2(p0, p1);
        } else {
            int j = i - NE4;
            if (j < 3 * (DIM * DIM) / 4) {
                int sel = j >> 12;             // DIM*DIM/4 = 4096 = 1<<12
                int jj = j & 4095;
                const float* S = (sel == 0) ? W : ((sel == 1) ? A_db : A_c);
                unsigned short* Dst = (sel == 0) ? Wt_h : ((sel == 1) ? At_db_h : At_c_h);
                int o = jj * 4;
                int n = o >> 7, k0 = o & 127;
                unsigned int p0 = (unsigned int)f2bf(S[(k0 + 0) * DIM + n]) |
                                  ((unsigned int)f2bf(S[(k0 + 1) * DIM + n]) << 16);
                unsigned int p1 = (unsigned int)f2bf(S[(k0 + 2) * DIM + n]) |
                                  ((unsigned int)f2bf(S[(k0 + 3) * DIM + n]) << 16);
                *(uint2*)(Dst + n * DIM + k0) = make_uint2(p0, p1);
            }
        }
        return;
    }
    // ---- w_h[r,n,:] = bf16(sum_b comp[r,b]*basis[b,n,:])
    if (!use_w) return;
    if (t < NREL * NBASIS) sc[t] = comp[t];
    __syncthreads();
    int i = (bb - NB_HIST - NB_CONV) * 256 + t;
    int n = i >> 5, d4 = i & 31;
    float4 bv[NBASIS];
#pragma unroll
    for (int b = 0; b < NBASIS; ++b)
        bv[b] = ((const float4*)(basis + ((size_t)b * N_ENT + n) * DIM))[d4];
#pragma unroll
    for (int r = 0; r < NREL; ++r) {
        float4 acc = make_float4(0.f, 0.f, 0.f, 0.f);
#pragma unroll
        for (int b = 0; b < NBASIS; ++b) {
            float c = sc[r * NBASIS + b];
            acc.x += c * bv[b].x; acc.y += c * bv[b].y;
            acc.z += c * bv[b].z; acc.w += c * bv[b].w;
        }
        unsigned int p0 = (unsigned int)f2bf(acc.x) | ((unsigned int)f2bf(acc.y) << 16);
        unsigned int p1 = (unsigned int)f2bf(acc.z) | ((unsigned int)f2bf(acc.w) << 16);
        *(uint2*)(w_h + ((size_t)r * N_ENT + n) * DIM + d4 * 4) = make_uint2(p0, p1);
    }
}

// ============================ dispatch 2: two exclusive scans (+dinv) + xw MFMA filling idle CUs
__device__ void scan_block(const int* __restrict__ cnt, int n, int* __restrict__ rowptr) {
    __shared__ int part[1024];
    int t = threadIdx.x;
    int per = (n + 1023) / 1024;
    int s0 = t * per;
    int sum = 0;
    for (int i = 0; i < per; ++i) {
        int idx = s0 + i;
        if (idx < n) sum += cnt[idx];
    }
    part[t] = sum;
    __syncthreads();
    for (int off = 1; off < 1024; off <<= 1) {
        int v = (t >= off) ? part[t - off] : 0;
        __syncthreads();
        part[t] += v;
        __syncthreads();
    }
    int run = part[t] - sum;
    for (int i = 0; i < per; ++i) {
        int idx = s0 + i;
        if (idx < n) {
            rowptr[idx] = run;
            run += cnt[idx];
        }
    }
    if (t == 1023) rowptr[n] = part[1023];
}

__global__ __launch_bounds__(1024) void scan2_kernel(const int* __restrict__ cnt_e,
                                                     const int* __restrict__ cnt_c,
                                                     int* __restrict__ rowptr_e,
                                                     int* __restrict__ rowptr_c,
                                                     float* __restrict__ dinv,
                                                     const unsigned short* __restrict__ emb_h,
                                                     const unsigned short* __restrict__ Wt_h,
                                                     unsigned short* __restrict__ xw_h) {
    int bb = blockIdx.x;
    if (bb == 0) {
        scan_block(cnt_e, N_ENT, rowptr_e);
        return;
    }
    if (bb == 1) {
        scan_block(cnt_c, N_CON, rowptr_c);
        for (int i = threadIdx.x; i < N_CON; i += 1024)
            dinv[i] = rsqrtf((float)(cnt_c[i] + 1));
        return;
    }
    // ---- xw_h = bf16(emb @ W) via MFMA; 16 waves cover 128 rows x 128 cols
    int t = threadIdx.x;
    int wave = t >> 6, lane = t & 63;
    int m0 = (bb - 2) * 128 + (wave >> 2) * 32;
    int n0 = (wave & 3) * 32;
    int am = lane & 31, ak = (lane >> 5) * 8;
    int mrow = m0 + am;
    bool mv = mrow < N_CON;
    const unsigned short* Ar = emb_h + (size_t)mrow * DIM + ak;
    const unsigned short* Br = Wt_h + (size_t)(n0 + am) * DIM + ak;
    facc16 acc;
#pragma unroll
    for (int r = 0; r < 16; ++r) acc[r] = 0.f;
#pragma unroll
    for (int s = 0; s < 8; ++s) {
        bfrag8 a;
#pragma unroll
        for (int j = 0; j < 8; ++j) a[j] = 0;
        if (mv) a = *(const bfrag8*)(Ar + s * 16);
        bfrag8 b = *(const bfrag8*)(Br + s * 16);
        acc = __builtin_amdgcn_mfma_f32_32x32x16_bf16(a, b, acc, 0, 0, 0);
    }
    int col = lane & 31;
    int g4 = (lane >> 5) * 4;
#pragma unroll
    for (int r = 0; r < 16; ++r) {
        int m = m0 + (r & 3) + ((r >> 2) << 3) + g4;
        if (m < N_CON) xw_h[(size_t)m * DIM + n0 + col] = f2bf(acc[r]);
    }
}

// ============================ dispatch 3: scatter only (pure writes, ordinals precomputed)
__global__ __launch_bounds__(256) void scatter_kernel(const int* __restrict__ db_eidx,
                                                      const int* __restrict__ db_etype,
                                                      const int* __restrict__ con_eidx,
                                                      const int* __restrict__ ord_db,
                                                      const int* __restrict__ ord_con,
                                                      const int* __restrict__ rowptr_e,
                                                      const int* __restrict__ rowptr_c,
                                                      int* __restrict__ elist_e,
                                                      int* __restrict__ elist_c) {
    int e = blockIdx.x * 256 + threadIdx.x;
    if (e < EDB) {
        int dst = db_eidx[EDB + e];
        elist_e[rowptr_e[dst] + ord_db[e]] = db_eidx[e] | (db_etype[e] << 18);
    } else if (e < EDB + ECON) {
        int ee = e - EDB;
        int dst = con_eidx[ECON + ee];
        elist_c[rowptr_c[dst] + ord_con[ee]] = con_eidx[ee];
    }
}

// ============================ dispatch 4: both graph gathers (block-range fused)
__global__ __launch_bounds__(256) void gathers_kernel(const int* __restrict__ rowptr_e,
                                                      const int* __restrict__ elist_e,
                                                      const unsigned short* __restrict__ w_h,
                                                      const float* __restrict__ root,
                                                      const float* __restrict__ bias,
                                                      unsigned short* __restrict__ dbf_h,
                                                      const int* __restrict__ rowptr_c,
                                                      const int* __restrict__ elist_c,
                                                      const float* __restrict__ dinv,
                                                      const unsigned short* __restrict__ xw_h,
                                                      const float* __restrict__ gcn_b,
                                                      unsigned short* __restrict__ conf_h) {
    int bb = blockIdx.x;
    int lane = threadIdx.x & 63;
    if (bb < NB_RG) {
        int wid = bb * 4 + (threadIdx.x >> 6);
        if (wid >= N_ENT) return;
        int beg = rowptr_e[wid], end = rowptr_e[wid + 1];
        float a0 = 0.f, a1 = 0.f;
        int p = beg;
        for (; p + 3 < end; p += 4) {
            int v0 = elist_e[p], v1 = elist_e[p + 1], v2 = elist_e[p + 2], v3 = elist_e[p + 3];
            unsigned int k0 = *(const unsigned int*)(w_h + ((size_t)(v0 >> 18) * N_ENT + (v0 & 0x3FFFF)) * DIM + lane * 2);
            unsigned int k1 = *(const unsigned int*)(w_h + ((size_t)(v1 >> 18) * N_ENT + (v1 & 0x3FFFF)) * DIM + lane * 2);
            unsigned int k2 = *(const unsigned int*)(w_h + ((size_t)(v2 >> 18) * N_ENT + (v2 & 0x3FFFF)) * DIM + lane * 2);
            unsigned int k3 = *(const unsigned int*)(w_h + ((size_t)(v3 >> 18) * N_ENT + (v3 & 0x3FFFF)) * DIM + lane * 2);
            a0 += bf2f(k0 & 0xFFFF) + bf2f(k1 & 0xFFFF) + bf2f(k2 & 0xFFFF) + bf2f(k3 & 0xFFFF);
            a1 += bf2f(k0 >> 16)    + bf2f(k1 >> 16)    + bf2f(k2 >> 16)    + bf2f(k3 >> 16);
        }
        for (; p < end; ++p) {
            int v = elist_e[p];
            unsigned int k = *(const unsigned int*)(w_h + ((size_t)(v >> 18) * N_ENT + (v & 0x3FFFF)) * DIM + lane * 2);
            a0 += bf2f(k & 0xFFFF);
            a1 += bf2f(k >> 16);
        }
        float inv = 1.f / fmaxf((float)(end - beg), 1.f);
        size_t base = (size_t)wid * DIM + lane * 2;
        float f0 = a0 * inv + root[base]     + bias[lane * 2];
        float f1 = a1 * inv + root[base + 1] + bias[lane * 2 + 1];
        *(unsigned int*)(dbf_h + base) = (unsigned int)f2bf(f0) | ((unsigned int)f2bf(f1) << 16);
    } else {
        int wid = (bb - NB_RG) * 4 + (threadIdx.x >> 6);
        if (wid >= N_CON) return;
        int beg = rowptr_c[wid], end = rowptr_c[wid + 1];
        float a0 = 0.f, a1 = 0.f;
        int p = beg;
        for (; p + 3 < end; p += 4) {
            int s0 = elist_c[p], s1 = elist_c[p + 1], s2 = elist_c[p + 2], s3 = elist_c[p + 3];
            float n0 = dinv[s0], n1 = dinv[s1], n2 = dinv[s2], n3 = dinv[s3];
            unsigned int k0 = *(const unsigned int*)(xw_h + (size_t)s0 * DIM + lane * 2);
            unsigned int k1 = *(const unsigned int*)(xw_h + (size_t)s1 * DIM + lane * 2);
            unsigned int k2 = *(const unsigned int*)(xw_h + (size_t)s2 * DIM + lane * 2);
            unsigned int k3 = *(const unsigned int*)(xw_h + (size_t)s3 * DIM + lane * 2);
            a0 += n0 * bf2f(k0 & 0xFFFF) + n1 * bf2f(k1 & 0xFFFF) + n2 * bf2f(k2 & 0xFFFF) + n3 * bf2f(k3 & 0xFFFF);
            a1 += n0 * bf2f(k0 >> 16)    + n1 * bf2f(k1 >> 16)    + n2 * bf2f(k2 >> 16)    + n3 * bf2f(k3 >> 16);
        }
        for (; p < end; ++p) {
            int s = elist_c[p];
            float nm = dinv[s];
            unsigned int k = *(const unsigned int*)(xw_h + (size_t)s * DIM + lane * 2);
            a0 += nm * bf2f(k & 0xFFFF);
            a1 += nm * bf2f(k >> 16);
        }
        float dv = dinv[wid];
        unsigned int ks = *(const unsigned int*)(xw_h + (size_t)wid * DIM + lane * 2);
        size_t base = (size_t)wid * DIM + lane * 2;
        float f0 = dv * a0 + dv * dv * bf2f(ks & 0xFFFF) + gcn_b[lane * 2];
        float f1 = dv * a1 + dv * dv * bf2f(ks >> 16)    + gcn_b[lane * 2 + 1];
        *(unsigned int*)(conf_h + base) = (unsigned int)f2bf(f0) | ((unsigned int)f2bf(f1) << 16);
    }
}

// fallback when ws too small for w_h: RGCN gather straight from fp32 basis
__global__ __launch_bounds__(256) void rgcn_gather_basis(const int* __restrict__ rowptr,
                                                         const int* __restrict__ elist,
                                                         const float* __restrict__ basis,
                                                         const float* __restrict__ comp,
                                                         const float* __restrict__ root,
                                                         const float* __restrict__ bias,
                                                         unsigned short* __restrict__ dbf_h) {
    int wid  = blockIdx.x * 4 + (threadIdx.x >> 6);
    int lane = threadIdx.x & 63;
    if (wid >= N_ENT) return;
    int beg = rowptr[wid], end = rowptr[wid + 1];
    float a0 = 0.f, a1 = 0.f;
    for (int p = beg; p < end; ++p) {
        int v = elist[p];
        int src = v & 0x3FFFF, ty = v >> 18;
        const float* c = comp + ty * NBASIS;
#pragma unroll
        for (int b = 0; b < NBASIS; ++b) {
            const float* bp = basis + ((size_t)b * N_ENT + src) * DIM;
            a0 += c[b] * bp[lane * 2];
            a1 += c[b] * bp[lane * 2 + 1];
        }
    }
    float inv = 1.f / fmaxf((float)(end - beg), 1.f);
    size_t base = (size_t)wid * DIM + lane * 2;
    float f0 = a0 * inv + root[base]     + bias[lane * 2];
    float f1 = a1 * inv + root[base + 1] + bias[lane * 2 + 1];
    *(unsigned int*)(dbf_h + base) = (unsigned int)f2bf(f0) | ((unsigned int)f2bf(f1) << 16);
}

// ============================ dispatch 5: attention scores for ALL rows via MFMA
// e[n] = sum_d v[d] * tanh( (feats[n,:] @ A)[d] ), computed for every entity/concept.
// score(gather(rows)) == gather(score(rows)) since e is a per-row function.
__global__ __launch_bounds__(256) void escore_kernel(const unsigned short* __restrict__ dbf_h,
                                                     const unsigned short* __restrict__ conf_h,
                                                     const unsigned short* __restrict__ At_db_h,
                                                     const float* __restrict__ v_db,
                                                     const unsigned short* __restrict__ At_c_h,
                                                     const float* __restrict__ v_c,
                                                     float* __restrict__ e_db,
                                                     float* __restrict__ e_con) {
    __shared__ float part[4][32];
    int t = threadIdx.x, bb = blockIdx.x;
    int wave = t >> 6, lane = t & 63;
    const unsigned short* feats;
    const unsigned short* At;
    const float* v;
    float* eo;
    int m0, nrow;
    if (bb < NB_EDB) {
        feats = dbf_h;  At = At_db_h; v = v_db; eo = e_db;  m0 = bb * 32;             nrow = N_ENT;
    } else {
        feats = conf_h; At = At_c_h;  v = v_c;  eo = e_con; m0 = (bb - NB_EDB) * 32;  nrow = N_CON;
    }
    int n0 = wave * 32;                 // 4 waves cover all 128 output dims
    int am = lane & 31, ak = (lane >> 5) * 8;
    int mrow = m0 + am;
    bool mv = mrow < nrow;
    const unsigned short* Ar = feats + (size_t)mrow * DIM + ak;
    const unsigned short* Br = At + (size_t)(n0 + am) * DIM + ak;
    facc16 acc;
#pragma unroll
    for (int r = 0; r < 16; ++r) acc[r] = 0.f;
#pragma unroll
    for (int s = 0; s < 8; ++s) {
        bfrag8 a;
#pragma unroll
        for (int j = 0; j < 8; ++j) a[j] = 0;
        if (mv) a = *(const bfrag8*)(Ar + s * 16);
        bfrag8 b = *(const bfrag8*)(Br + s * 16);
        acc = __builtin_amdgcn_mfma_f32_32x32x16_bf16(a, b, acc, 0, 0, 0);
    }
    int col = lane & 31, g = lane >> 5;
    float vn = v[n0 + col];
    // each acc[r] is one (row, col) element; reduce tanh(x)*v over the 32 cols (lanes)
#pragma unroll
    for (int r = 0; r < 16; ++r) {
        float x = tanhf(acc[r]) * vn;
#pragma unroll
        for (int off = 16; off >= 1; off >>= 1) x += __shfl_xor(x, off, 32);
        if (col == 0) {
            int row = (r & 3) + ((r >> 2) << 3) + (g << 2);
            part[wave][row] = x;
        }
    }
    __syncthreads();
    if (t < 32) {
        int m = m0 + t;
        if (m < nrow)
            eo[m] = part[0][t] + part[1][t] + part[2][t] + part[3][t];
    }
}

// ============================ dispatch 6: softmax + weighted sums + gated fusion per sample
__global__ __launch_bounds__(256) void attn_fusion_kernel(const unsigned short* __restrict__ dbf_h,
                                                          const unsigned short* __restrict__ conf_h,
                                                          const float* __restrict__ e_db,
                                                          const float* __restrict__ e_con,
                                                          const int* __restrict__ seed_pad,
                                                          const int* __restrict__ seed_lens,
                                                          const int* __restrict__ concept_mask,
                                                          const float* __restrict__ Wu, const float* __restrict__ bu,
                                                          const float* __restrict__ gw, const float* __restrict__ gb,
                                                          const float* __restrict__ Wi, const float* __restrict__ bi,
                                                          unsigned short* __restrict__ uemb_h,
                                                          unsigned short* __restrict__ cone_h,
                                                          float* __restrict__ maskv) {
    __shared__ int srow[SSEED];
    __shared__ int crow[LCON];
    __shared__ float a_db[SSEED], a_con[LCON];
    __shared__ float du[DIM], cu[DIM], red[DIM];
    int b = blockIdx.x, t = threadIdx.x;
    int wave = t >> 6, lane = t & 63;
    int len = seed_lens[b];
    if (wave == 0) {
        // db softmax over S=32 (lanes 0..31)
        float e = -1e30f;
        if (lane < SSEED) {
            int rv = seed_pad[b * SSEED + lane];
            srow[lane] = rv;
            if (lane < len) e = e_db[rv];
        }
        float m = e;
#pragma unroll
        for (int off = 16; off >= 1; off >>= 1) m = fmaxf(m, __shfl_xor(m, off, 32));
        float p = (lane < SSEED) ? __expf(e - m) : 0.f;
        float s = p;
#pragma unroll
        for (int off = 16; off >= 1; off >>= 1) s += __shfl_xor(s, off, 32);
        if (lane < SSEED) a_db[lane] = p / s;
    } else if (wave == 1) {
        // con softmax over LC=50 (lanes 0..49)
        float e = -1e30f;
        if (lane < LCON) {
            int rv = concept_mask[b * LCON + lane];
            crow[lane] = rv;
            if (rv != 0) e = e_con[rv];
        }
        float m = e;
#pragma unroll
        for (int off = 32; off >= 1; off >>= 1) m = fmaxf(m, __shfl_xor(m, off, 64));
        float p = (lane < LCON) ? __expf(e - m) : 0.f;
        float s = p;
#pragma unroll
        for (int off = 32; off >= 1; off >>= 1) s += __shfl_xor(s, off, 64);
        if (lane < LCON) a_con[lane] = p / s;
    }
    __syncthreads();
    // weighted row sums: threads 0..127 -> du, 128..255 -> cu
    if (t < DIM) {
        float acc = 0.f;
#pragma unroll
        for (int s = 0; s < SSEED; ++s)
            acc += a_db[s] * bf2f((unsigned int)dbf_h[(size_t)srow[s] * DIM + t]);
        du[t] = (len > 0) ? acc : 0.f;
    } else {
        int d = t - DIM;
        float acc = 0.f;
#pragma unroll
        for (int s = 0; s < LCON; ++s)
            acc += a_con[s] * bf2f((unsigned int)conf_h[(size_t)crow[s] * DIM + d]);
        cu[d] = acc;
    }
    __syncthreads();
    // fusion
    if (t < DIM) {
        float u = bu[t];
        const float* wr = Wu + t * 2 * DIM;
        for (int k = 0; k < DIM; ++k) u += cu[k] * wr[k];
        for (int k = 0; k < DIM; ++k) u += du[k] * wr[DIM + k];
        red[t] = u * gw[t];
    }
    __syncthreads();
    for (int s2 = 64; s2 > 0; s2 >>= 1) {
        if (t < s2) red[t] += red[t + s2];
        __syncthreads();
    }
    if (t < DIM) {
        float gate = 1.f / (1.f + __expf(-(red[0] + gb[0])));
        uemb_h[b * DIM + t] = f2bf(gate * du[t] + (1.f - gate) * cu[t]);
        float ce = bi[t];
        const float* wi = Wi + t * DIM;
        for (int k = 0; k < DIM; ++k) ce += cu[k] * wi[k];
        cone_h[b * DIM + t] = f2bf(ce);
    }
    if (t == 0) maskv[b] = (len > 0) ? 1.f : 0.f;
}

// ============================ dispatch 7: fused scoring GEMMs (MFMA) + CE/ssq partials
__global__ __launch_bounds__(256) void score_mfma(const unsigned short* __restrict__ dbf_h,
                                                  const unsigned short* __restrict__ uemb_h,
                                                  const unsigned short* __restrict__ cone_h,
                                                  const float* __restrict__ en_b,
                                                  const float* __restrict__ info_b,
                                                  const float* __restrict__ db_vec,
                                                  float* __restrict__ escore,
                                                  float* __restrict__ partM,
                                                  float* __restrict__ partS,
                                                  float* __restrict__ partQ) {
    int wave = threadIdx.x >> 6, lane = threadIdx.x & 63;
    int nt = blockIdx.x * 4 + wave;
    if (nt >= NTILE) return;
    int b0 = blockIdx.y * 32;
    int n0 = nt * 32;
    int am = lane & 31, ak = (lane >> 5) * 8;
    int nb = n0 + am;
    bool bvalid = nb < N_ENT;
    const unsigned short* Au = uemb_h + (size_t)(b0 + am) * DIM + ak;
    const unsigned short* Ac = cone_h + (size_t)(b0 + am) * DIM + ak;
    const unsigned short* Bp = dbf_h + (size_t)nb * DIM + ak;
    facc16 accE, accD;
#pragma unroll
    for (int r = 0; r < 16; ++r) { accE[r] = 0.f; accD[r] = 0.f; }
#pragma unroll
    for (int s = 0; s < 8; ++s) {
        bfrag8 au = *(const bfrag8*)(Au + s * 16);
        bfrag8 ac = *(const bfrag8*)(Ac + s * 16);
        bfrag8 bb;
#pragma unroll
        for (int j = 0; j < 8; ++j) bb[j] = 0;
        if (bvalid) bb = *(const bfrag8*)(Bp + s * 16);
        accE = __builtin_amdgcn_mfma_f32_32x32x16_bf16(au, bb, accE, 0, 0, 0);
        accD = __builtin_amdgcn_mfma_f32_32x32x16_bf16(ac, bb, accD, 0, 0, 0);
    }
    int col = lane & 31;
    int n = n0 + col;
    bool nv = n < N_ENT;
    float enb = nv ? en_b[n] : 0.f;
    float inb = nv ? info_b[n] : 0.f;
    int g4 = (lane >> 5) * 4;
#pragma unroll
    for (int r = 0; r < 16; ++r) {
        int b = b0 + (r & 3) + ((r >> 2) << 3) + g4;
        float e = accE[r] + enb;
        if (nv) escore[(size_t)b * N_ENT + n] = e;
        float ev = nv ? e : -1e30f;
        float mx = ev;
#pragma unroll
        for (int off = 16; off >= 1; off >>= 1) mx = fmaxf(mx, __shfl_xor(mx, off, 64));
        float ex = nv ? __expf(e - mx) : 0.f;
        float sm = ex;
#pragma unroll
        for (int off = 16; off >= 1; off >>= 1) sm += __shfl_xor(sm, off, 64);
        float d = nv ? (accD[r] + inb - db_vec[(size_t)b * N_ENT + n]) : 0.f;
        float q = d * d;
#pragma unroll
        for (int off = 16; off >= 1; off >>= 1) q += __shfl_xor(q, off, 64);
        if (col == 0) {
            partM[(size_t)b * NTILE + nt] = mx;
            partS[(size_t)b * NTILE + nt] = sm;
            partQ[(size_t)b * NTILE + nt] = q;
        }
    }
}

// ============================ dispatch 8: CE finalize from partials
__global__ __launch_bounds__(256) void ce_final(const float* __restrict__ partM,
                                                const float* __restrict__ partS,
                                                const float* __restrict__ partQ,
                                                const float* __restrict__ escore,
                                                const int* __restrict__ labels,
                                                const float* __restrict__ rec,
                                                float* __restrict__ rloss,
                                                float* __restrict__ ssqv) {
    __shared__ float red[256], red2[256];
    int b = blockIdx.x, t = threadIdx.x;
    const float* pm = partM + (size_t)b * NTILE;
    const float* ps = partS + (size_t)b * NTILE;
    const float* pq = partQ + (size_t)b * NTILE;
    float mx = -1e30f;
    for (int i = t; i < NTILE; i += 256) mx = fmaxf(mx, pm[i]);
    red[t] = mx;
    __syncthreads();
    for (int s2 = 128; s2 > 0; s2 >>= 1) {
        if (t < s2) red[t] = fmaxf(red[t], red[t + s2]);
        __syncthreads();
    }
    float M = red[0];
    __syncthreads();
    float s = 0.f, q = 0.f;
    for (int i = t; i < NTILE; i += 256) {
        s += ps[i] * __expf(pm[i] - M);
        q += pq[i];
    }
    red[t] = s; red2[t] = q;
    __syncthreads();
    for (int s2 = 128; s2 > 0; s2 >>= 1) {
        if (t < s2) { red[t] += red[t + s2]; red2[t] += red2[t + s2]; }
        __syncthreads();
    }
    if (t == 0) {
        float lse = M + logf(red[0]);
        float ce  = -(escore[(size_t)b * N_ENT + labels[b]] - lse);
        rloss[b]  = ce * rec[b];
        ssqv[b]   = red2[0];
    }
}

// ============================ dispatch 9: final scalar reduction
__global__ __launch_bounds__(256) void final_kernel(const float* __restrict__ rloss,
                                                    const float* __restrict__ sumsq,
                                                    const float* __restrict__ maskv,
                                                    float* __restrict__ out) {
    __shared__ float r1[256], r2[256];
    int t = threadIdx.x;
    r1[t] = rloss[t];
    r2[t] = sumsq[t] * maskv[t];
    __syncthreads();
    for (int s2 = 128; s2 > 0; s2 >>= 1) {
        if (t < s2) { r1[t] += r1[t + s2]; r2[t] += r2[t + s2]; }
        __syncthreads();
    }
    if (t == 0) {
        float rec_loss = r1[0];
        float info = r2[0] / (float)BATCH;
        out[0] = rec_loss + 0.025f * info;
        out[1 + (size_t)BATCH * N_ENT] = rec_loss;
    }
}

// ============================ launch
extern "C" void kernel_launch(void* const* d_in, const int* in_sizes, int n_in,
                              void* d_out, int out_size, void* d_ws, size_t ws_size,
                              hipStream_t stream) {
    (void)in_sizes; (void)n_in; (void)out_size;
    const int*   concept_mask  = (const int*)d_in[0];
    const int*   seed_pad      = (const int*)d_in[1];
    const int*   seed_lens     = (const int*)d_in[2];
    const int*   db_eidx       = (const int*)d_in[3];
    const int*   db_etype      = (const int*)d_in[4];
    const int*   con_eidx      = (const int*)d_in[5];
    const float* db_vec        = (const float*)d_in[6];
    const int*   labels        = (const int*)d_in[7];
    const float* rec           = (const float*)d_in[8];
    const float* concept_emb   = (const float*)d_in[9];
    const float* basis         = (const float*)d_in[10];
    const float* comp          = (const float*)d_in[11];
    const float* rgcn_root     = (const float*)d_in[12];
    const float* rgcn_bias     = (const float*)d_in[13];
    const float* gcn_w         = (const float*)d_in[14];
    const float* gcn_b         = (const float*)d_in[15];
    const float* attn_a        = (const float*)d_in[16];
    const float* attn_b        = (const float*)d_in[17];
    const float* attn_a_db     = (const float*)d_in[18];
    const float* attn_b_db     = (const float*)d_in[19];
    const float* user_norm_w   = (const float*)d_in[20];
    const float* user_norm_b   = (const float*)d_in[21];
    const float* gate_norm_w   = (const float*)d_in[22];
    const float* gate_norm_b   = (const float*)d_in[23];
    const float* info_con_w    = (const float*)d_in[24];
    const float* info_con_b    = (const float*)d_in[25];
    const float* info_out_db_b = (const float*)d_in[26];
    const float* output_en_b   = (const float*)d_in[27];

    float* ws = (float*)d_ws;
    size_t off = 0;
    auto alloc = [&](size_t n) { float* p = ws + off; off += (n + 255) & ~(size_t)255; return p; };
    float* dinv   = alloc(N_CON);
    float* maskv  = alloc(BATCH);
    float* rls    = alloc(BATCH);
    float* ssqv   = alloc(BATCH);
    float* partM  = alloc((size_t)BATCH * NTILE);
    float* partS  = alloc((size_t)BATCH * NTILE);
    float* partQ  = alloc((size_t)BATCH * NTILE);
    int* cnt_e    = (int*)alloc(N_ENT + N_CON);     // contiguous for one memset
    int* cnt_c    = cnt_e + N_ENT;
    int* rowptr_e = (int*)alloc(N_ENT + 1);
    int* rowptr_c = (int*)alloc(N_CON + 1);
    int* ord_db   = (int*)alloc(EDB);
    int* ord_con  = (int*)alloc(ECON);
    int* elist_e  = (int*)alloc(EDB);
    int* elist_c  = (int*)alloc(ECON);
    unsigned short* dbf_h  = (unsigned short*)alloc((size_t)N_ENT * DIM / 2);
    unsigned short* conf_h = (unsigned short*)alloc((size_t)N_CON * DIM / 2 + 128);
    unsigned short* xw_h   = (unsigned short*)alloc((size_t)N_CON * DIM / 2 + 128);
    unsigned short* emb_h  = (unsigned short*)alloc((size_t)N_CON * DIM / 2 + 128);
    unsigned short* Wt_h   = (unsigned short*)alloc(DIM * DIM / 2);
    unsigned short* uemb_h = (unsigned short*)alloc(BATCH * DIM / 2);
    unsigned short* cone_h = (unsigned short*)alloc(BATCH * DIM / 2);
    float* e_db   = alloc(N_ENT);
    float* e_con  = alloc(N_CON);
    unsigned short* At_db_h = (unsigned short*)alloc(DIM * DIM / 2);
    unsigned short* At_c_h  = (unsigned short*)alloc(DIM * DIM / 2);
    size_t w_elems = ((size_t)NREL * N_ENT * DIM) / 2;   // bf16 in float-units
    int use_w = (off + w_elems) * sizeof(float) <= ws_size;
    unsigned short* w_h = (unsigned short*)(ws + off);

    float* out    = (float*)d_out;
    float* escore = out + 1;

    (void)hipMemsetAsync(cnt_e, 0, (N_ENT + N_CON) * sizeof(int), stream);

    prep_kernel<<<NB_HIST + NB_CONV + NB_WCOMP, 256, 0, stream>>>(
        db_eidx + EDB, con_eidx + ECON, concept_emb, gcn_w, attn_a_db, attn_a,
        basis, comp, cnt_e, cnt_c, ord_db, ord_con, emb_h, Wt_h, At_db_h, At_c_h,
        w_h, use_w);
    scan2_kernel<<<2 + NB_XW, 1024, 0, stream>>>(cnt_e, cnt_c, rowptr_e, rowptr_c, dinv,
                                                 emb_h, Wt_h, xw_h);
    scatter_kernel<<<NB_HIST, 256, 0, stream>>>(db_eidx, db_etype, con_eidx,
                                                ord_db, ord_con, rowptr_e, rowptr_c,
                                                elist_e, elist_c);
    gathers_kernel<<<NB_RG + NB_GG, 256, 0, stream>>>(rowptr_e, elist_e, w_h, rgcn_root, rgcn_bias,
                                                      dbf_h, rowptr_c, elist_c, dinv, xw_h, gcn_b, conf_h);
    if (!use_w) {
        rgcn_gather_basis<<<NB_RG, 256, 0, stream>>>(rowptr_e, elist_e, basis, comp,
                                                     rgcn_root, rgcn_bias, dbf_h);
    }
    escore_kernel<<<NB_EDB + NB_ECON, 256, 0, stream>>>(dbf_h, conf_h, At_db_h, attn_b_db,
                                                        At_c_h, attn_b, e_db, e_con);
    attn_fusion_kernel<<<BATCH, 256, 0, stream>>>(dbf_h, conf_h, e_db, e_con,
                                                  seed_pad, seed_lens, concept_mask,
                                                  user_norm_w, user_norm_b, gate_norm_w, gate_norm_b,
                                                  info_con_w, info_con_b, uemb_h, cone_h, maskv);
    dim3 sg((NTILE + 3) / 4, BATCH / 32);
    score_mfma<<<sg, 256, 0, stream>>>(dbf_h, uemb_h, cone_h, output_en_b, info_out_db_b, db_vec,
                                       escore, partM, partS, partQ);
    ce_final<<<BATCH, 256, 0, stream>>>(partM, partS, partQ, escore, labels, rec, rls, ssqv);
    final_kernel<<<1, 256, 0, stream>>>(rls, ssqv, maskv, out);
}

// Round 3
// 516.398 us; speedup vs baseline: 1.1457x; 1.0022x over previous
//
#include <hip/hip_runtime.h>

#define N_ENT  30000
#define N_CON  29309
#define DIM    128
#define NBASIS 8
#define NREL   12
#define BATCH  256
#define LCON   50
#define SSEED  32
#define EDB    300000
#define ECON   200000
#define NTILE  938   // ceil(N_ENT/32)

#define NE4      ((N_CON * DIM) / 4)          // 937888 (exact)
#define NB_HIST  ((EDB + ECON + 255) / 256)   // 1954
#define NB_CONV  ((NE4 + 3 * (DIM * DIM / 4) + 255) / 256)
#define NB_WCOMP ((N_ENT * 32) / 256)         // 3750
#define NB_XW    ((N_CON + 127) / 128)        // 229 (1024-thread blocks, 128 rows each)
#define NB_RG    ((N_ENT + 3) / 4)            // 7500
#define NB_GG    ((N_CON + 3) / 4)            // 7328
#define NB_EDB   ((N_ENT + 31) / 32)          // 938
#define NB_ECON  ((N_CON + 31) / 32)          // 916

typedef __attribute__((ext_vector_type(8)))  short bfrag8;
typedef __attribute__((ext_vector_type(16))) float facc16;

__device__ __forceinline__ unsigned short f2bf(float f) {
    unsigned int u = __float_as_uint(f);
    u += 0x7FFFu + ((u >> 16) & 1u);
    return (unsigned short)(u >> 16);
}
__device__ __forceinline__ float bf2f(unsigned int h) {
    return __uint_as_float(h << 16);
}

// ============================ dispatch 1: hist (with ordinals) + bf16 conversions
__global__ __launch_bounds__(256) void prep_kernel(const int* __restrict__ db_dst,
                                                   const int* __restrict__ con_dst,
                                                   const float* __restrict__ emb,
                                                   const float* __restrict__ W,
                                                   const float* __restrict__ A_db,
                                                   const float* __restrict__ A_c,
                                                   int* __restrict__ cnt_e, int* __restrict__ cnt_c,
                                                   int* __restrict__ ord_db, int* __restrict__ ord_con,
                                                   unsigned short* __restrict__ emb_h,
                                                   unsigned short* __restrict__ Wt_h,
                                                   unsigned short* __restrict__ At_db_h,
                                                   unsigned short* __restrict__ At_c_h) {
    int t = threadIdx.x, bb = blockIdx.x;
    if (bb < NB_HIST) {
        int e = bb * 256 + t;
        if (e < EDB) {
            ord_db[e] = atomicAdd(cnt_e + db_dst[e], 1);
        } else if (e < EDB + ECON) {
            int ee = e - EDB;
            ord_con[ee] = atomicAdd(cnt_c + con_dst[ee], 1);
        }
        return;
    }
    int i = (bb - NB_HIST) * 256 + t;
    if (i < NE4) {
        float4 v = ((const float4*)emb)[i];
        unsigned int p0 = (unsigned int)f2bf(v.x) | ((unsigned int)f2bf(v.y) << 16);
        unsigned int p1 = (unsigned int)f2bf(v.z) | ((unsigned int)f2bf(v.w) << 16);
        *(uint2*)(emb_h + (size_t)i * 4) = make_uint2(p0, p1);
    } else {
        int j = i - NE4;
        if (j < 3 * (DIM * DIM) / 4) {
            int sel = j >> 12;             // DIM*DIM/4 = 4096 = 1<<12
            int jj = j & 4095;
            const float* S = (sel == 0) ? W : ((sel == 1) ? A_db : A_c);
            unsigned short* Dst = (sel == 0) ? Wt_h : ((sel == 1) ? At_db_h : At_c_h);
            int o = jj * 4;
            int n = o >> 7, k0 = o & 127;
            unsigned int p0 = (unsigned int)f2bf(S[(k0 + 0) * DIM + n]) |
                              ((unsigned int)f2bf(S[(k0 + 1) * DIM + n]) << 16);
            unsigned int p1 = (unsigned int)f2bf(S[(k0 + 2) * DIM + n]) |
                              ((unsigned int)f2bf(S[(k0 + 3) * DIM + n]) << 16);
            *(uint2*)(Dst + n * DIM + k0) = make_uint2(p0, p1);
        }
    }
}

// ============================ dispatch 2: two exclusive scans (+dinv) + xw MFMA filling idle CUs
__device__ void scan_block(const int* __restrict__ cnt, int n, int* __restrict__ rowptr) {
    __shared__ int part[1024];
    int t = threadIdx.x;
    int per = (n + 1023) / 1024;
    int s0 = t * per;
    int sum = 0;
    for (int i = 0; i < per; ++i) {
        int idx = s0 + i;
        if (idx < n) sum += cnt[idx];
    }
    part[t] = sum;
    __syncthreads();
    for (int off = 1; off < 1024; off <<= 1) {
        int v = (t >= off) ? part[t - off] : 0;
        __syncthreads();
        part[t] += v;
        __syncthreads();
    }
    int run = part[t] - sum;
    for (int i = 0; i < per; ++i) {
        int idx = s0 + i;
        if (idx < n) {
            rowptr[idx] = run;
            run += cnt[idx];
        }
    }
    if (t == 1023) rowptr[n] = part[1023];
}

__global__ __launch_bounds__(1024) void scan2_kernel(const int* __restrict__ cnt_e,
                                                     const int* __restrict__ cnt_c,
                                                     int* __restrict__ rowptr_e,
                                                     int* __restrict__ rowptr_c,
                                                     float* __restrict__ dinv,
                                                     const unsigned short* __restrict__ emb_h,
                                                     const unsigned short* __restrict__ Wt_h,
                                                     unsigned short* __restrict__ xw_h) {
    int bb = blockIdx.x;
    if (bb == 0) {
        scan_block(cnt_e, N_ENT, rowptr_e);
        return;
    }
    if (bb == 1) {
        scan_block(cnt_c, N_CON, rowptr_c);
        for (int i = threadIdx.x; i < N_CON; i += 1024)
            dinv[i] = rsqrtf((float)(cnt_c[i] + 1));
        return;
    }
    // ---- xw_h = bf16(emb @ W) via MFMA; 16 waves cover 128 rows x 128 cols
    int t = threadIdx.x;
    int wave = t >> 6, lane = t & 63;
    int m0 = (bb - 2) * 128 + (wave >> 2) * 32;
    int n0 = (wave & 3) * 32;
    int am = lane & 31, ak = (lane >> 5) * 8;
    int mrow = m0 + am;
    bool mv = mrow < N_CON;
    const unsigned short* Ar = emb_h + (size_t)mrow * DIM + ak;
    const unsigned short* Br = Wt_h + (size_t)(n0 + am) * DIM + ak;
    facc16 acc;
#pragma unroll
    for (int r = 0; r < 16; ++r) acc[r] = 0.f;
#pragma unroll
    for (int s = 0; s < 8; ++s) {
        bfrag8 a;
#pragma unroll
        for (int j = 0; j < 8; ++j) a[j] = 0;
        if (mv) a = *(const bfrag8*)(Ar + s * 16);
        bfrag8 b = *(const bfrag8*)(Br + s * 16);
        acc = __builtin_amdgcn_mfma_f32_32x32x16_bf16(a, b, acc, 0, 0, 0);
    }
    int col = lane & 31;
    int g4 = (lane >> 5) * 4;
#pragma unroll
    for (int r = 0; r < 16; ++r) {
        int m = m0 + (r & 3) + ((r >> 2) << 3) + g4;
        if (m < N_CON) xw_h[(size_t)m * DIM + n0 + col] = f2bf(acc[r]);
    }
}

// ============================ dispatch 3: scatter only (pure writes, ordinals precomputed)
__global__ __launch_bounds__(256) void scatter_kernel(const int* __restrict__ db_eidx,
                                                      const int* __restrict__ db_etype,
                                                      const int* __restrict__ con_eidx,
                                                      const int* __restrict__ ord_db,
                                                      const int* __restrict__ ord_con,
                                                      const int* __restrict__ rowptr_e,
                                                      const int* __restrict__ rowptr_c,
                                                      int* __restrict__ elist_e,
                                                      int* __restrict__ elist_c) {
    int e = blockIdx.x * 256 + threadIdx.x;
    if (e < EDB) {
        int dst = db_eidx[EDB + e];
        elist_e[rowptr_e[dst] + ord_db[e]] = db_eidx[e] | (db_etype[e] << 18);
    } else if (e < EDB + ECON) {
        int ee = e - EDB;
        int dst = con_eidx[ECON + ee];
        elist_c[rowptr_c[dst] + ord_con[ee]] = con_eidx[ee];
    }
}

// ============================ dispatch 4: wcomp (HBM-BW stream) || GCN gather (latency-bound)
// w_h layout: [ent][rel][dim] so the 12 per-entity rows are contiguous (3 KB span per n).
__global__ __launch_bounds__(256) void wcomp_gcn_kernel(const float* __restrict__ basis,
                                                        const float* __restrict__ comp,
                                                        unsigned short* __restrict__ w_h,
                                                        int use_w,
                                                        const int* __restrict__ rowptr_c,
                                                        const int* __restrict__ elist_c,
                                                        const float* __restrict__ dinv,
                                                        const unsigned short* __restrict__ xw_h,
                                                        const float* __restrict__ gcn_b,
                                                        unsigned short* __restrict__ conf_h) {
    int t = threadIdx.x, bb = blockIdx.x;
    if (bb < NB_WCOMP) {
        __shared__ float sc[NREL * NBASIS];
        if (!use_w) return;
        if (t < NREL * NBASIS) sc[t] = comp[t];
        __syncthreads();
        int i = bb * 256 + t;
        int n = i >> 5, d4 = i & 31;
        float4 bv[NBASIS];
#pragma unroll
        for (int b = 0; b < NBASIS; ++b)
            bv[b] = ((const float4*)(basis + ((size_t)b * N_ENT + n) * DIM))[d4];
#pragma unroll
        for (int r = 0; r < NREL; ++r) {
            float4 acc = make_float4(0.f, 0.f, 0.f, 0.f);
#pragma unroll
            for (int b = 0; b < NBASIS; ++b) {
                float c = sc[r * NBASIS + b];
                acc.x += c * bv[b].x; acc.y += c * bv[b].y;
                acc.z += c * bv[b].z; acc.w += c * bv[b].w;
            }
            unsigned int p0 = (unsigned int)f2bf(acc.x) | ((unsigned int)f2bf(acc.y) << 16);
            unsigned int p1 = (unsigned int)f2bf(acc.z) | ((unsigned int)f2bf(acc.w) << 16);
            *(uint2*)(w_h + ((size_t)n * NREL + r) * DIM + d4 * 4) = make_uint2(p0, p1);
        }
        return;
    }
    // ---- GCN gather (reads xw_h, elist_c; writes conf_h)
    int gb = bb - NB_WCOMP;
    int wid = gb * 4 + (t >> 6);
    if (wid >= N_CON) return;
    int lane = t & 63;
    int beg = rowptr_c[wid], end = rowptr_c[wid + 1];
    float a0 = 0.f, a1 = 0.f;
    int p = beg;
    for (; p + 3 < end; p += 4) {
        int s0 = elist_c[p], s1 = elist_c[p + 1], s2 = elist_c[p + 2], s3 = elist_c[p + 3];
        float n0 = dinv[s0], n1 = dinv[s1], n2 = dinv[s2], n3 = dinv[s3];
        unsigned int k0 = *(const unsigned int*)(xw_h + (size_t)s0 * DIM + lane * 2);
        unsigned int k1 = *(const unsigned int*)(xw_h + (size_t)s1 * DIM + lane * 2);
        unsigned int k2 = *(const unsigned int*)(xw_h + (size_t)s2 * DIM + lane * 2);
        unsigned int k3 = *(const unsigned int*)(xw_h + (size_t)s3 * DIM + lane * 2);
        a0 += n0 * bf2f(k0 & 0xFFFF) + n1 * bf2f(k1 & 0xFFFF) + n2 * bf2f(k2 & 0xFFFF) + n3 * bf2f(k3 & 0xFFFF);
        a1 += n0 * bf2f(k0 >> 16)    + n1 * bf2f(k1 >> 16)    + n2 * bf2f(k2 >> 16)    + n3 * bf2f(k3 >> 16);
    }
    for (; p < end; ++p) {
        int s = elist_c[p];
        float nm = dinv[s];
        unsigned int k = *(const unsigned int*)(xw_h + (size_t)s * DIM + lane * 2);
        a0 += nm * bf2f(k & 0xFFFF);
        a1 += nm * bf2f(k >> 16);
    }
    float dv = dinv[wid];
    unsigned int ks = *(const unsigned int*)(xw_h + (size_t)wid * DIM + lane * 2);
    size_t base = (size_t)wid * DIM + lane * 2;
    float f0 = dv * a0 + dv * dv * bf2f(ks & 0xFFFF) + gcn_b[lane * 2];
    float f1 = dv * a1 + dv * dv * bf2f(ks >> 16)    + gcn_b[lane * 2 + 1];
    *(unsigned int*)(conf_h + base) = (unsigned int)f2bf(f0) | ((unsigned int)f2bf(f1) << 16);
}

// shared escore body: e[n] = sum_d v[d] * tanh( (feats[n,:] @ A)[d] ) for 32 rows at m0
__device__ __forceinline__ void escore_body(const unsigned short* __restrict__ feats,
                                            const unsigned short* __restrict__ At,
                                            const float* __restrict__ v,
                                            float* __restrict__ eo,
                                            int m0, int nrow) {
    __shared__ float part[4][32];
    int t = threadIdx.x;
    int wave = t >> 6, lane = t & 63;
    int n0 = wave * 32;                 // 4 waves cover all 128 output dims
    int am = lane & 31, ak = (lane >> 5) * 8;
    int mrow = m0 + am;
    bool mv = mrow < nrow;
    const unsigned short* Ar = feats + (size_t)mrow * DIM + ak;
    const unsigned short* Br = At + (size_t)(n0 + am) * DIM + ak;
    facc16 acc;
#pragma unroll
    for (int r = 0; r < 16; ++r) acc[r] = 0.f;
#pragma unroll
    for (int s = 0; s < 8; ++s) {
        bfrag8 a;
#pragma unroll
        for (int j = 0; j < 8; ++j) a[j] = 0;
        if (mv) a = *(const bfrag8*)(Ar + s * 16);
        bfrag8 b = *(const bfrag8*)(Br + s * 16);
        acc = __builtin_amdgcn_mfma_f32_32x32x16_bf16(a, b, acc, 0, 0, 0);
    }
    int col = lane & 31, g = lane >> 5;
    float vn = v[n0 + col];
#pragma unroll
    for (int r = 0; r < 16; ++r) {
        float x = tanhf(acc[r]) * vn;
#pragma unroll
        for (int off = 16; off >= 1; off >>= 1) x += __shfl_xor(x, off, 32);
        if (col == 0) {
            int row = (r & 3) + ((r >> 2) << 3) + (g << 2);
            part[wave][row] = x;
        }
    }
    __syncthreads();
    if (t < 32) {
        int m = m0 + t;
        if (m < nrow)
            eo[m] = part[0][t] + part[1][t] + part[2][t] + part[3][t];
    }
}

// ============================ dispatch 5: RGCN gather (reads w_h) || concept escore (reads conf_h)
__global__ __launch_bounds__(256) void rgcn_escore_kernel(const int* __restrict__ rowptr_e,
                                                          const int* __restrict__ elist_e,
                                                          const unsigned short* __restrict__ w_h,
                                                          const float* __restrict__ root,
                                                          const float* __restrict__ bias,
                                                          unsigned short* __restrict__ dbf_h,
                                                          const unsigned short* __restrict__ conf_h,
                                                          const unsigned short* __restrict__ At_c_h,
                                                          const float* __restrict__ v_c,
                                                          float* __restrict__ e_con,
                                                          int use_w) {
    int bb = blockIdx.x;
    if (bb < NB_RG) {
        if (!use_w) return;   // fallback kernel handles RGCN gather
        int wid = bb * 4 + (threadIdx.x >> 6);
        int lane = threadIdx.x & 63;
        int beg = rowptr_e[wid], end = rowptr_e[wid + 1];
        float a0 = 0.f, a1 = 0.f;
        int p = beg;
        for (; p + 3 < end; p += 4) {
            int v0 = elist_e[p], v1 = elist_e[p + 1], v2 = elist_e[p + 2], v3 = elist_e[p + 3];
            unsigned int k0 = *(const unsigned int*)(w_h + ((size_t)(v0 & 0x3FFFF) * NREL + (v0 >> 18)) * DIM + lane * 2);
            unsigned int k1 = *(const unsigned int*)(w_h + ((size_t)(v1 & 0x3FFFF) * NREL + (v1 >> 18)) * DIM + lane * 2);
            unsigned int k2 = *(const unsigned int*)(w_h + ((size_t)(v2 & 0x3FFFF) * NREL + (v2 >> 18)) * DIM + lane * 2);
            unsigned int k3 = *(const unsigned int*)(w_h + ((size_t)(v3 & 0x3FFFF) * NREL + (v3 >> 18)) * DIM + lane * 2);
            a0 += bf2f(k0 & 0xFFFF) + bf2f(k1 & 0xFFFF) + bf2f(k2 & 0xFFFF) + bf2f(k3 & 0xFFFF);
            a1 += bf2f(k0 >> 16)    + bf2f(k1 >> 16)    + bf2f(k2 >> 16)    + bf2f(k3 >> 16);
        }
        for (; p < end; ++p) {
            int v = elist_e[p];
            unsigned int k = *(const unsigned int*)(w_h + ((size_t)(v & 0x3FFFF) * NREL + (v >> 18)) * DIM + lane * 2);
            a0 += bf2f(k & 0xFFFF);
            a1 += bf2f(k >> 16);
        }
        float inv = 1.f / fmaxf((float)(end - beg), 1.f);
        size_t base = (size_t)wid * DIM + lane * 2;
        float f0 = a0 * inv + root[base]     + bias[lane * 2];
        float f1 = a1 * inv + root[base + 1] + bias[lane * 2 + 1];
        *(unsigned int*)(dbf_h + base) = (unsigned int)f2bf(f0) | ((unsigned int)f2bf(f1) << 16);
        return;
    }
    escore_body(conf_h, At_c_h, v_c, e_con, (bb - NB_RG) * 32, N_CON);
}

// fallback when ws too small for w_h: RGCN gather straight from fp32 basis
__global__ __launch_bounds__(256) void rgcn_gather_basis(const int* __restrict__ rowptr,
                                                         const int* __restrict__ elist,
                                                         const float* __restrict__ basis,
                                                         const float* __restrict__ comp,
                                                         const float* __restrict__ root,
                                                         const float* __restrict__ bias,
                                                         unsigned short* __restrict__ dbf_h) {
    int wid  = blockIdx.x * 4 + (threadIdx.x >> 6);
    int lane = threadIdx.x & 63;
    if (wid >= N_ENT) return;
    int beg = rowptr[wid], end = rowptr[wid + 1];
    float a0 = 0.f, a1 = 0.f;
    for (int p = beg; p < end; ++p) {
        int v = elist[p];
        int src = v & 0x3FFFF, ty = v >> 18;
        const float* c = comp + ty * NBASIS;
#pragma unroll
        for (int b = 0; b < NBASIS; ++b) {
            const float* bp = basis + ((size_t)b * N_ENT + src) * DIM;
            a0 += c[b] * bp[lane * 2];
            a1 += c[b] * bp[lane * 2 + 1];
        }
    }
    float inv = 1.f / fmaxf((float)(end - beg), 1.f);
    size_t base = (size_t)wid * DIM + lane * 2;
    float f0 = a0 * inv + root[base]     + bias[lane * 2];
    float f1 = a1 * inv + root[base + 1] + bias[lane * 2 + 1];
    *(unsigned int*)(dbf_h + base) = (unsigned int)f2bf(f0) | ((unsigned int)f2bf(f1) << 16);
}

// ============================ dispatch 6: db-entity escore
__global__ __launch_bounds__(256) void escore_db_kernel(const unsigned short* __restrict__ dbf_h,
                                                        const unsigned short* __restrict__ At_db_h,
                                                        const float* __restrict__ v_db,
                                                        float* __restrict__ e_db) {
    escore_body(dbf_h, At_db_h, v_db, e_db, blockIdx.x * 32, N_ENT);
}

// ============================ dispatch 7: softmax + weighted sums + gated fusion per sample
__global__ __launch_bounds__(256) void attn_fusion_kernel(const unsigned short* __restrict__ dbf_h,
                                                          const unsigned short* __restrict__ conf_h,
                                                          const float* __restrict__ e_db,
                                                          const float* __restrict__ e_con,
                                                          const int* __restrict__ seed_pad,
                                                          const int* __restrict__ seed_lens,
                                                          const int* __restrict__ concept_mask,
                                                          const float* __restrict__ Wu, const float* __restrict__ bu,
                                                          const float* __restrict__ gw, const float* __restrict__ gb,
                                                          const float* __restrict__ Wi, const float* __restrict__ bi,
                                                          unsigned short* __restrict__ uemb_h,
                                                          unsigned short* __restrict__ cone_h,
                                                          float* __restrict__ maskv) {
    __shared__ int srow[SSEED];
    __shared__ int crow[LCON];
    __shared__ float a_db[SSEED], a_con[LCON];
    __shared__ float du[DIM], cu[DIM], red[DIM];
    int b = blockIdx.x, t = threadIdx.x;
    int wave = t >> 6, lane = t & 63;
    int len = seed_lens[b];
    if (wave == 0) {
        // db softmax over S=32 (lanes 0..31)
        float e = -1e30f;
        if (lane < SSEED) {
            int rv = seed_pad[b * SSEED + lane];
            srow[lane] = rv;
            if (lane < len) e = e_db[rv];
        }
        float m = e;
#pragma unroll
        for (int off = 16; off >= 1; off >>= 1) m = fmaxf(m, __shfl_xor(m, off, 32));
        float p = (lane < SSEED) ? __expf(e - m) : 0.f;
        float s = p;
#pragma unroll
        for (int off = 16; off >= 1; off >>= 1) s += __shfl_xor(s, off, 32);
        if (lane < SSEED) a_db[lane] = p / s;
    } else if (wave == 1) {
        // con softmax over LC=50 (lanes 0..49)
        float e = -1e30f;
        if (lane < LCON) {
            int rv = concept_mask[b * LCON + lane];
            crow[lane] = rv;
            if (rv != 0) e = e_con[rv];
        }
        float m = e;
#pragma unroll
        for (int off = 32; off >= 1; off >>= 1) m = fmaxf(m, __shfl_xor(m, off, 64));
        float p = (lane < LCON) ? __expf(e - m) : 0.f;
        float s = p;
#pragma unroll
        for (int off = 32; off >= 1; off >>= 1) s += __shfl_xor(s, off, 64);
        if (lane < LCON) a_con[lane] = p / s;
    }
    __syncthreads();
    // weighted row sums: threads 0..127 -> du, 128..255 -> cu
    if (t < DIM) {
        float acc = 0.f;
#pragma unroll
        for (int s = 0; s < SSEED; ++s)
            acc += a_db[s] * bf2f((unsigned int)dbf_h[(size_t)srow[s] * DIM + t]);
        du[t] = (len > 0) ? acc : 0.f;
    } else {
        int d = t - DIM;
        float acc = 0.f;
#pragma unroll
        for (int s = 0; s < LCON; ++s)
            acc += a_con[s] * bf2f((unsigned int)conf_h[(size_t)crow[s] * DIM + d]);
        cu[d] = acc;
    }
    __syncthreads();
    // fusion
    if (t < DIM) {
        float u = bu[t];
        const float* wr = Wu + t * 2 * DIM;
        for (int k = 0; k < DIM; ++k) u += cu[k] * wr[k];
        for (int k = 0; k < DIM; ++k) u += du[k] * wr[DIM + k];
        red[t] = u * gw[t];
    }
    __syncthreads();
    for (int s2 = 64; s2 > 0; s2 >>= 1) {
        if (t < s2) red[t] += red[t + s2];
        __syncthreads();
    }
    if (t < DIM) {
        float gate = 1.f / (1.f + __expf(-(red[0] + gb[0])));
        uemb_h[b * DIM + t] = f2bf(gate * du[t] + (1.f - gate) * cu[t]);
        float ce = bi[t];
        const float* wi = Wi + t * DIM;
        for (int k = 0; k < DIM; ++k) ce += cu[k] * wi[k];
        cone_h[b * DIM + t] = f2bf(ce);
    }
    if (t == 0) maskv[b] = (len > 0) ? 1.f : 0.f;
}

// ============================ dispatch 8: fused scoring GEMMs (MFMA) + CE/ssq partials
__global__ __launch_bounds__(256) void score_mfma(const unsigned short* __restrict__ dbf_h,
                                                  const unsigned short* __restrict__ uemb_h,
                                                  const unsigned short* __restrict__ cone_h,
                                                  const float* __restrict__ en_b,
                                                  const float* __restrict__ info_b,
                                                  const float* __restrict__ db_vec,
                                                  float* __restrict__ escore,
                                                  float* __restrict__ partM,
                                                  float* __restrict__ partS,
                                                  float* __restrict__ partQ) {
    int wave = threadIdx.x >> 6, lane = threadIdx.x & 63;
    int nt = blockIdx.x * 4 + wave;
    if (nt >= NTILE) return;
    int b0 = blockIdx.y * 32;
    int n0 = nt * 32;
    int am = lane & 31, ak = (lane >> 5) * 8;
    int nb = n0 + am;
    bool bvalid = nb < N_ENT;
    const unsigned short* Au = uemb_h + (size_t)(b0 + am) * DIM + ak;
    const unsigned short* Ac = cone_h + (size_t)(b0 + am) * DIM + ak;
    const unsigned short* Bp = dbf_h + (size_t)nb * DIM + ak;
    facc16 accE, accD;
#pragma unroll
    for (int r = 0; r < 16; ++r) { accE[r] = 0.f; accD[r] = 0.f; }
#pragma unroll
    for (int s = 0; s < 8; ++s) {
        bfrag8 au = *(const bfrag8*)(Au + s * 16);
        bfrag8 ac = *(const bfrag8*)(Ac + s * 16);
        bfrag8 bb;
#pragma unroll
        for (int j = 0; j < 8; ++j) bb[j] = 0;
        if (bvalid) bb = *(const bfrag8*)(Bp + s * 16);
        accE = __builtin_amdgcn_mfma_f32_32x32x16_bf16(au, bb, accE, 0, 0, 0);
        accD = __builtin_amdgcn_mfma_f32_32x32x16_bf16(ac, bb, accD, 0, 0, 0);
    }
    int col = lane & 31;
    int n = n0 + col;
    bool nv = n < N_ENT;
    float enb = nv ? en_b[n] : 0.f;
    float inb = nv ? info_b[n] : 0.f;
    int g4 = (lane >> 5) * 4;
#pragma unroll
    for (int r = 0; r < 16; ++r) {
        int b = b0 + (r & 3) + ((r >> 2) << 3) + g4;
        float e = accE[r] + enb;
        if (nv) escore[(size_t)b * N_ENT + n] = e;
        float ev = nv ? e : -1e30f;
        float mx = ev;
#pragma unroll
        for (int off = 16; off >= 1; off >>= 1) mx = fmaxf(mx, __shfl_xor(mx, off, 64));
        float ex = nv ? __expf(e - mx) : 0.f;
        float sm = ex;
#pragma unroll
        for (int off = 16; off >= 1; off >>= 1) sm += __shfl_xor(sm, off, 64);
        float d = nv ? (accD[r] + inb - db_vec[(size_t)b * N_ENT + n]) : 0.f;
        float q = d * d;
#pragma unroll
        for (int off = 16; off >= 1; off >>= 1) q += __shfl_xor(q, off, 64);
        if (col == 0) {
            partM[(size_t)b * NTILE + nt] = mx;
            partS[(size_t)b * NTILE + nt] = sm;
            partQ[(size_t)b * NTILE + nt] = q;
        }
    }
}

// ============================ dispatch 9: CE finalize from partials
__global__ __launch_bounds__(256) void ce_final(const float* __restrict__ partM,
                                                const float* __restrict__ partS,
                                                const float* __restrict__ partQ,
                                                const float* __restrict__ escore,
                                                const int* __restrict__ labels,
                                                const float* __restrict__ rec,
                                                float* __restrict__ rloss,
                                                float* __restrict__ ssqv) {
    __shared__ float red[256], red2[256];
    int b = blockIdx.x, t = threadIdx.x;
    const float* pm = partM + (size_t)b * NTILE;
    const float* ps = partS + (size_t)b * NTILE;
    const float* pq = partQ + (size_t)b * NTILE;
    float mx = -1e30f;
    for (int i = t; i < NTILE; i += 256) mx = fmaxf(mx, pm[i]);
    red[t] = mx;
    __syncthreads();
    for (int s2 = 128; s2 > 0; s2 >>= 1) {
        if (t < s2) red[t] = fmaxf(red[t], red[t + s2]);
        __syncthreads();
    }
    float M = red[0];
    __syncthreads();
    float s = 0.f, q = 0.f;
    for (int i = t; i < NTILE; i += 256) {
        s += ps[i] * __expf(pm[i] - M);
        q += pq[i];
    }
    red[t] = s; red2[t] = q;
    __syncthreads();
    for (int s2 = 128; s2 > 0; s2 >>= 1) {
        if (t < s2) { red[t] += red[t + s2]; red2[t] += red2[t + s2]; }
        __syncthreads();
    }
    if (t == 0) {
        float lse = M + logf(red[0]);
        float ce  = -(escore[(size_t)b * N_ENT + labels[b]] - lse);
        rloss[b]  = ce * rec[b];
        ssqv[b]   = red2[0];
    }
}

// ============================ dispatch 10: final scalar reduction
__global__ __launch_bounds__(256) void final_kernel(const float* __restrict__ rloss,
                                                    const float* __restrict__ sumsq,
                                                    const float* __restrict__ maskv,
                                                    float* __restrict__ out) {
    __shared__ float r1[256], r2[256];
    int t = threadIdx.x;
    r1[t] = rloss[t];
    r2[t] = sumsq[t] * maskv[t];
    __syncthreads();
    for (int s2 = 128; s2 > 0; s2 >>= 1) {
        if (t < s2) { r1[t] += r1[t + s2]; r2[t] += r2[t + s2]; }
        __syncthreads();
    }
    if (t == 0) {
        float rec_loss = r1[0];
        float info = r2[0] / (float)BATCH;
        out[0] = rec_loss + 0.025f * info;
        out[1 + (size_t)BATCH * N_ENT] = rec_loss;
    }
}

// ============================ launch
extern "C" void kernel_launch(void* const* d_in, const int* in_sizes, int n_in,
                              void* d_out, int out_size, void* d_ws, size_t ws_size,
                              hipStream_t stream) {
    (void)in_sizes; (void)n_in; (void)out_size;
    const int*   concept_mask  = (const int*)d_in[0];
    const int*   seed_pad      = (const int*)d_in[1];
    const int*   seed_lens     = (const int*)d_in[2];
    const int*   db_eidx       = (const int*)d_in[3];
    const int*   db_etype      = (const int*)d_in[4];
    const int*   con_eidx      = (const int*)d_in[5];
    const float* db_vec        = (const float*)d_in[6];
    const int*   labels        = (const int*)d_in[7];
    const float* rec           = (const float*)d_in[8];
    const float* concept_emb   = (const float*)d_in[9];
    const float* basis         = (const float*)d_in[10];
    const float* comp          = (const float*)d_in[11];
    const float* rgcn_root     = (const float*)d_in[12];
    const float* rgcn_bias     = (const float*)d_in[13];
    const float* gcn_w         = (const float*)d_in[14];
    const float* gcn_b         = (const float*)d_in[15];
    const float* attn_a        = (const float*)d_in[16];
    const float* attn_b        = (const float*)d_in[17];
    const float* attn_a_db     = (const float*)d_in[18];
    const float* attn_b_db     = (const float*)d_in[19];
    const float* user_norm_w   = (const float*)d_in[20];
    const float* user_norm_b   = (const float*)d_in[21];
    const float* gate_norm_w   = (const float*)d_in[22];
    const float* gate_norm_b   = (const float*)d_in[23];
    const float* info_con_w    = (const float*)d_in[24];
    const float* info_con_b    = (const float*)d_in[25];
    const float* info_out_db_b = (const float*)d_in[26];
    const float* output_en_b   = (const float*)d_in[27];

    float* ws = (float*)d_ws;
    size_t off = 0;
    auto alloc = [&](size_t n) { float* p = ws + off; off += (n + 255) & ~(size_t)255; return p; };
    float* dinv   = alloc(N_CON);
    float* maskv  = alloc(BATCH);
    float* rls    = alloc(BATCH);
    float* ssqv   = alloc(BATCH);
    float* partM  = alloc((size_t)BATCH * NTILE);
    float* partS  = alloc((size_t)BATCH * NTILE);
    float* partQ  = alloc((size_t)BATCH * NTILE);
    int* cnt_e    = (int*)alloc(N_ENT + N_CON);     // contiguous for one memset
    int* cnt_c    = cnt_e + N_ENT;
    int* rowptr_e = (int*)alloc(N_ENT + 1);
    int* rowptr_c = (int*)alloc(N_CON + 1);
    int* ord_db   = (int*)alloc(EDB);
    int* ord_con  = (int*)alloc(ECON);
    int* elist_e  = (int*)alloc(EDB);
    int* elist_c  = (int*)alloc(ECON);
    unsigned short* dbf_h  = (unsigned short*)alloc((size_t)N_ENT * DIM / 2);
    unsigned short* conf_h = (unsigned short*)alloc((size_t)N_CON * DIM / 2 + 128);
    unsigned short* xw_h   = (unsigned short*)alloc((size_t)N_CON * DIM / 2 + 128);
    unsigned short* emb_h  = (unsigned short*)alloc((size_t)N_CON * DIM / 2 + 128);
    unsigned short* Wt_h   = (unsigned short*)alloc(DIM * DIM / 2);
    unsigned short* uemb_h = (unsigned short*)alloc(BATCH * DIM / 2);
    unsigned short* cone_h = (unsigned short*)alloc(BATCH * DIM / 2);
    float* e_db   = alloc(N_ENT);
    float* e_con  = alloc(N_CON);
    unsigned short* At_db_h = (unsigned short*)alloc(DIM * DIM / 2);
    unsigned short* At_c_h  = (unsigned short*)alloc(DIM * DIM / 2);
    size_t w_elems = ((size_t)NREL * N_ENT * DIM) / 2;   // bf16 in float-units
    int use_w = (off + w_elems) * sizeof(float) <= ws_size;
    unsigned short* w_h = (unsigned short*)(ws + off);

    float* out    = (float*)d_out;
    float* escore = out + 1;

    (void)hipMemsetAsync(cnt_e, 0, (N_ENT + N_CON) * sizeof(int), stream);

    prep_kernel<<<NB_HIST + NB_CONV, 256, 0, stream>>>(
        db_eidx + EDB, con_eidx + ECON, concept_emb, gcn_w, attn_a_db, attn_a,
        cnt_e, cnt_c, ord_db, ord_con, emb_h, Wt_h, At_db_h, At_c_h);
    scan2_kernel<<<2 + NB_XW, 1024, 0, stream>>>(cnt_e, cnt_c, rowptr_e, rowptr_c, dinv,
                                                 emb_h, Wt_h, xw_h);
    scatter_kernel<<<NB_HIST, 256, 0, stream>>>(db_eidx, db_etype, con_eidx,
                                                ord_db, ord_con, rowptr_e, rowptr_c,
                                                elist_e, elist_c);
    wcomp_gcn_kernel<<<NB_WCOMP + NB_GG, 256, 0, stream>>>(basis, comp, w_h, use_w,
                                                           rowptr_c, elist_c, dinv, xw_h,
                                                           gcn_b, conf_h);
    if (!use_w) {
        rgcn_gather_basis<<<NB_RG, 256, 0, stream>>>(rowptr_e, elist_e, basis, comp,
                                                     rgcn_root, rgcn_bias, dbf_h);
    }
    rgcn_escore_kernel<<<NB_RG + NB_ECON, 256, 0, stream>>>(rowptr_e, elist_e, w_h,
                                                            rgcn_root, rgcn_bias, dbf_h,
                                                            conf_h, At_c_h, attn_b, e_con, use_w);
    escore_db_kernel<<<NB_EDB, 256, 0, stream>>>(dbf_h, At_db_h, attn_b_db, e_db);
    attn_fusion_kernel<<<BATCH, 256, 0, stream>>>(dbf_h, conf_h, e_db, e_con,
                                                  seed_pad, seed_lens, concept_mask,
                                                  user_norm_w, user_norm_b, gate_norm_w, gate_norm_b,
                                                  info_con_w, info_con_b, uemb_h, cone_h, maskv);
    dim3 sg((NTILE + 3) / 4, BATCH / 32);
    score_mfma<<<sg, 256, 0, stream>>>(dbf_h, uemb_h, cone_h, output_en_b, info_out_db_b, db_vec,
                                       escore, partM, partS, partQ);
    ce_final<<<BATCH, 256, 0, stream>>>(partM, partS, partQ, escore, labels, rec, rls, ssqv);
    final_kernel<<<1, 256, 0, stream>>>(rls, ssqv, maskv, out);
}

// Round 4
// 506.876 us; speedup vs baseline: 1.1673x; 1.0188x over previous
//
#include <hip/hip_runtime.h>

#define N_ENT  30000
#define N_CON  29309
#define DIM    128
#define NBASIS 8
#define NREL   12
#define BATCH  256
#define LCON   50
#define SSEED  32
#define EDB    300000
#define ECON   200000
#define NTILE  938   // ceil(N_ENT/32)

#define NE4      ((N_CON * DIM) / 4)          // 937888 (exact)
#define NB_HIST  ((EDB + ECON + 255) / 256)   // 1954
#define NB_CONV  ((NE4 + 3 * (DIM * DIM / 4) + 255) / 256)   // 3712
#define NB_WCOMP ((N_ENT * 32) / 256)         // 3750
#define NB_PREP  (NB_HIST * 5)                // 9770: slot0=hist, slot1/2=conv, slot3/4=wcomp
#define NB_XW    ((N_CON + 127) / 128)        // 229 (1024-thread blocks, 128 rows each)
#define NB_RG    ((N_ENT + 3) / 4)            // 7500
#define NB_GG    ((N_CON + 3) / 4)            // 7328
#define NB_EDB   ((N_ENT + 31) / 32)          // 938
#define NB_ECON  ((N_CON + 31) / 32)          // 916

typedef __attribute__((ext_vector_type(8)))  short bfrag8;
typedef __attribute__((ext_vector_type(16))) float facc16;

__device__ __forceinline__ unsigned short f2bf(float f) {
    unsigned int u = __float_as_uint(f);
    u += 0x7FFFu + ((u >> 16) & 1u);
    return (unsigned short)(u >> 16);
}
__device__ __forceinline__ float bf2f(unsigned int h) {
    return __uint_as_float(h << 16);
}

// ============================ dispatch 1: hist (x) conv (x) wcomp — modulo-interleaved roles
// Role by bb%5 so every scheduling wave mixes atomic-latency, convert, and BW-stream blocks.
__global__ __launch_bounds__(256) void prep_kernel(const int* __restrict__ db_dst,
                                                   const int* __restrict__ con_dst,
                                                   const float* __restrict__ emb,
                                                   const float* __restrict__ W,
                                                   const float* __restrict__ A_db,
                                                   const float* __restrict__ A_c,
                                                   const float* __restrict__ basis,
                                                   const float* __restrict__ comp,
                                                   int* __restrict__ cnt_e, int* __restrict__ cnt_c,
                                                   int* __restrict__ ord_db, int* __restrict__ ord_con,
                                                   unsigned short* __restrict__ emb_h,
                                                   unsigned short* __restrict__ Wt_h,
                                                   unsigned short* __restrict__ At_db_h,
                                                   unsigned short* __restrict__ At_c_h,
                                                   unsigned short* __restrict__ w_h,
                                                   int use_w) {
    __shared__ float sc[NREL * NBASIS];
    int t = threadIdx.x, bb = blockIdx.x;
    int g = bb / 5, slot = bb % 5;
    if (slot == 0) {
        // ---- histogram with ordinals (g < NB_HIST by construction)
        int e = g * 256 + t;
        if (e < EDB) {
            ord_db[e] = atomicAdd(cnt_e + db_dst[e], 1);
        } else if (e < EDB + ECON) {
            int ee = e - EDB;
            ord_con[ee] = atomicAdd(cnt_c + con_dst[ee], 1);
        }
        return;
    }
    if (slot <= 2) {
        // ---- bf16 conversions
        int cb = g * 2 + (slot - 1);
        if (cb >= NB_CONV) return;
        int i = cb * 256 + t;
        if (i < NE4) {
            float4 v = ((const float4*)emb)[i];
            unsigned int p0 = (unsigned int)f2bf(v.x) | ((unsigned int)f2bf(v.y) << 16);
            unsigned int p1 = (unsigned int)f2bf(v.z) | ((unsigned int)f2bf(v.w) << 16);
            *(uint2*)(emb_h + (size_t)i * 4) = make_uint2(p0, p1);
        } else {
            int j = i - NE4;
            if (j < 3 * (DIM * DIM) / 4) {
                int sel = j >> 12;             // DIM*DIM/4 = 4096 = 1<<12
                int jj = j & 4095;
                const float* S = (sel == 0) ? W : ((sel == 1) ? A_db : A_c);
                unsigned short* Dst = (sel == 0) ? Wt_h : ((sel == 1) ? At_db_h : At_c_h);
                int o = jj * 4;
                int n = o >> 7, k0 = o & 127;
                unsigned int p0 = (unsigned int)f2bf(S[(k0 + 0) * DIM + n]) |
                                  ((unsigned int)f2bf(S[(k0 + 1) * DIM + n]) << 16);
                unsigned int p1 = (unsigned int)f2bf(S[(k0 + 2) * DIM + n]) |
                                  ((unsigned int)f2bf(S[(k0 + 3) * DIM + n]) << 16);
                *(uint2*)(Dst + n * DIM + k0) = make_uint2(p0, p1);
            }
        }
        return;
    }
    // ---- wcomp: w_h[n][r][:] = bf16(sum_b comp[r,b]*basis[b,n,:])
    if (!use_w) return;
    int wb = g * 2 + (slot - 3);
    if (wb >= NB_WCOMP) return;
    if (t < NREL * NBASIS) sc[t] = comp[t];
    __syncthreads();
    int i = wb * 256 + t;
    int n = i >> 5, d4 = i & 31;
    float4 bv[NBASIS];
#pragma unroll
    for (int b = 0; b < NBASIS; ++b)
        bv[b] = ((const float4*)(basis + ((size_t)b * N_ENT + n) * DIM))[d4];
#pragma unroll
    for (int r = 0; r < NREL; ++r) {
        float4 acc = make_float4(0.f, 0.f, 0.f, 0.f);
#pragma unroll
        for (int b = 0; b < NBASIS; ++b) {
            float c = sc[r * NBASIS + b];
            acc.x += c * bv[b].x; acc.y += c * bv[b].y;
            acc.z += c * bv[b].z; acc.w += c * bv[b].w;
        }
        unsigned int p0 = (unsigned int)f2bf(acc.x) | ((unsigned int)f2bf(acc.y) << 16);
        unsigned int p1 = (unsigned int)f2bf(acc.z) | ((unsigned int)f2bf(acc.w) << 16);
        *(uint2*)(w_h + ((size_t)n * NREL + r) * DIM + d4 * 4) = make_uint2(p0, p1);
    }
}

// ============================ dispatch 2: two exclusive scans (+dinv) + xw MFMA filling idle CUs
__device__ void scan_block(const int* __restrict__ cnt, int n, int* __restrict__ rowptr) {
    __shared__ int part[1024];
    int t = threadIdx.x;
    int per = (n + 1023) / 1024;
    int s0 = t * per;
    int sum = 0;
    for (int i = 0; i < per; ++i) {
        int idx = s0 + i;
        if (idx < n) sum += cnt[idx];
    }
    part[t] = sum;
    __syncthreads();
    for (int off = 1; off < 1024; off <<= 1) {
        int v = (t >= off) ? part[t - off] : 0;
        __syncthreads();
        part[t] += v;
        __syncthreads();
    }
    int run = part[t] - sum;
    for (int i = 0; i < per; ++i) {
        int idx = s0 + i;
        if (idx < n) {
            rowptr[idx] = run;
            run += cnt[idx];
        }
    }
    if (t == 1023) rowptr[n] = part[1023];
}

__global__ __launch_bounds__(1024) void scan2_kernel(const int* __restrict__ cnt_e,
                                                     const int* __restrict__ cnt_c,
                                                     int* __restrict__ rowptr_e,
                                                     int* __restrict__ rowptr_c,
                                                     float* __restrict__ dinv,
                                                     const unsigned short* __restrict__ emb_h,
                                                     const unsigned short* __restrict__ Wt_h,
                                                     unsigned short* __restrict__ xw_h) {
    int bb = blockIdx.x;
    if (bb == 0) {
        scan_block(cnt_e, N_ENT, rowptr_e);
        return;
    }
    if (bb == 1) {
        scan_block(cnt_c, N_CON, rowptr_c);
        for (int i = threadIdx.x; i < N_CON; i += 1024)
            dinv[i] = rsqrtf((float)(cnt_c[i] + 1));
        return;
    }
    // ---- xw_h = bf16(emb @ W) via MFMA; 16 waves cover 128 rows x 128 cols
    int t = threadIdx.x;
    int wave = t >> 6, lane = t & 63;
    int m0 = (bb - 2) * 128 + (wave >> 2) * 32;
    int n0 = (wave & 3) * 32;
    int am = lane & 31, ak = (lane >> 5) * 8;
    int mrow = m0 + am;
    bool mv = mrow < N_CON;
    const unsigned short* Ar = emb_h + (size_t)mrow * DIM + ak;
    const unsigned short* Br = Wt_h + (size_t)(n0 + am) * DIM + ak;
    facc16 acc;
#pragma unroll
    for (int r = 0; r < 16; ++r) acc[r] = 0.f;
#pragma unroll
    for (int s = 0; s < 8; ++s) {
        bfrag8 a;
#pragma unroll
        for (int j = 0; j < 8; ++j) a[j] = 0;
        if (mv) a = *(const bfrag8*)(Ar + s * 16);
        bfrag8 b = *(const bfrag8*)(Br + s * 16);
        acc = __builtin_amdgcn_mfma_f32_32x32x16_bf16(a, b, acc, 0, 0, 0);
    }
    int col = lane & 31;
    int g4 = (lane >> 5) * 4;
#pragma unroll
    for (int r = 0; r < 16; ++r) {
        int m = m0 + (r & 3) + ((r >> 2) << 3) + g4;
        if (m < N_CON) xw_h[(size_t)m * DIM + n0 + col] = f2bf(acc[r]);
    }
}

// ============================ dispatch 3: scatter only (pure writes, ordinals precomputed)
__global__ __launch_bounds__(256) void scatter_kernel(const int* __restrict__ db_eidx,
                                                      const int* __restrict__ db_etype,
                                                      const int* __restrict__ con_eidx,
                                                      const int* __restrict__ ord_db,
                                                      const int* __restrict__ ord_con,
                                                      const int* __restrict__ rowptr_e,
                                                      const int* __restrict__ rowptr_c,
                                                      int* __restrict__ elist_e,
                                                      int* __restrict__ elist_c) {
    int e = blockIdx.x * 256 + threadIdx.x;
    if (e < EDB) {
        int dst = db_eidx[EDB + e];
        elist_e[rowptr_e[dst] + ord_db[e]] = db_eidx[e] | (db_etype[e] << 18);
    } else if (e < EDB + ECON) {
        int ee = e - EDB;
        int dst = con_eidx[ECON + ee];
        elist_c[rowptr_c[dst] + ord_con[ee]] = con_eidx[ee];
    }
}

// ============================ dispatch 4: RGCN gather (x) GCN gather — parity-interleaved
__global__ __launch_bounds__(256) void gathers_kernel(const int* __restrict__ rowptr_e,
                                                      const int* __restrict__ elist_e,
                                                      const unsigned short* __restrict__ w_h,
                                                      const float* __restrict__ root,
                                                      const float* __restrict__ bias,
                                                      unsigned short* __restrict__ dbf_h,
                                                      const int* __restrict__ rowptr_c,
                                                      const int* __restrict__ elist_c,
                                                      const float* __restrict__ dinv,
                                                      const unsigned short* __restrict__ xw_h,
                                                      const float* __restrict__ gcn_b,
                                                      unsigned short* __restrict__ conf_h,
                                                      int use_w) {
    int bb = blockIdx.x;
    int pair = bb >> 1;
    int lane = threadIdx.x & 63;
    if ((bb & 1) == 0) {
        // ---- RGCN gather (pair < 7500 exactly)
        if (!use_w) return;   // fallback kernel handles RGCN gather
        int wid = pair * 4 + (threadIdx.x >> 6);
        int beg = rowptr_e[wid], end = rowptr_e[wid + 1];
        float a0 = 0.f, a1 = 0.f;
        int p = beg;
        for (; p + 3 < end; p += 4) {
            int v0 = elist_e[p], v1 = elist_e[p + 1], v2 = elist_e[p + 2], v3 = elist_e[p + 3];
            unsigned int k0 = *(const unsigned int*)(w_h + ((size_t)(v0 & 0x3FFFF) * NREL + (v0 >> 18)) * DIM + lane * 2);
            unsigned int k1 = *(const unsigned int*)(w_h + ((size_t)(v1 & 0x3FFFF) * NREL + (v1 >> 18)) * DIM + lane * 2);
            unsigned int k2 = *(const unsigned int*)(w_h + ((size_t)(v2 & 0x3FFFF) * NREL + (v2 >> 18)) * DIM + lane * 2);
            unsigned int k3 = *(const unsigned int*)(w_h + ((size_t)(v3 & 0x3FFFF) * NREL + (v3 >> 18)) * DIM + lane * 2);
            a0 += bf2f(k0 & 0xFFFF) + bf2f(k1 & 0xFFFF) + bf2f(k2 & 0xFFFF) + bf2f(k3 & 0xFFFF);
            a1 += bf2f(k0 >> 16)    + bf2f(k1 >> 16)    + bf2f(k2 >> 16)    + bf2f(k3 >> 16);
        }
        for (; p < end; ++p) {
            int v = elist_e[p];
            unsigned int k = *(const unsigned int*)(w_h + ((size_t)(v & 0x3FFFF) * NREL + (v >> 18)) * DIM + lane * 2);
            a0 += bf2f(k & 0xFFFF);
            a1 += bf2f(k >> 16);
        }
        float inv = 1.f / fmaxf((float)(end - beg), 1.f);
        size_t base = (size_t)wid * DIM + lane * 2;
        float f0 = a0 * inv + root[base]     + bias[lane * 2];
        float f1 = a1 * inv + root[base + 1] + bias[lane * 2 + 1];
        *(unsigned int*)(dbf_h + base) = (unsigned int)f2bf(f0) | ((unsigned int)f2bf(f1) << 16);
        return;
    }
    // ---- GCN gather
    if (pair >= NB_GG) return;
    int wid = pair * 4 + (threadIdx.x >> 6);
    if (wid >= N_CON) return;
    int beg = rowptr_c[wid], end = rowptr_c[wid + 1];
    float a0 = 0.f, a1 = 0.f;
    int p = beg;
    for (; p + 3 < end; p += 4) {
        int s0 = elist_c[p], s1 = elist_c[p + 1], s2 = elist_c[p + 2], s3 = elist_c[p + 3];
        float n0 = dinv[s0], n1 = dinv[s1], n2 = dinv[s2], n3 = dinv[s3];
        unsigned int k0 = *(const unsigned int*)(xw_h + (size_t)s0 * DIM + lane * 2);
        unsigned int k1 = *(const unsigned int*)(xw_h + (size_t)s1 * DIM + lane * 2);
        unsigned int k2 = *(const unsigned int*)(xw_h + (size_t)s2 * DIM + lane * 2);
        unsigned int k3 = *(const unsigned int*)(xw_h + (size_t)s3 * DIM + lane * 2);
        a0 += n0 * bf2f(k0 & 0xFFFF) + n1 * bf2f(k1 & 0xFFFF) + n2 * bf2f(k2 & 0xFFFF) + n3 * bf2f(k3 & 0xFFFF);
        a1 += n0 * bf2f(k0 >> 16)    + n1 * bf2f(k1 >> 16)    + n2 * bf2f(k2 >> 16)    + n3 * bf2f(k3 >> 16);
    }
    for (; p < end; ++p) {
        int s = elist_c[p];
        float nm = dinv[s];
        unsigned int k = *(const unsigned int*)(xw_h + (size_t)s * DIM + lane * 2);
        a0 += nm * bf2f(k & 0xFFFF);
        a1 += nm * bf2f(k >> 16);
    }
    float dv = dinv[wid];
    unsigned int ks = *(const unsigned int*)(xw_h + (size_t)wid * DIM + lane * 2);
    size_t base = (size_t)wid * DIM + lane * 2;
    float f0 = dv * a0 + dv * dv * bf2f(ks & 0xFFFF) + gcn_b[lane * 2];
    float f1 = dv * a1 + dv * dv * bf2f(ks >> 16)    + gcn_b[lane * 2 + 1];
    *(unsigned int*)(conf_h + base) = (unsigned int)f2bf(f0) | ((unsigned int)f2bf(f1) << 16);
}

// fallback when ws too small for w_h: RGCN gather straight from fp32 basis
__global__ __launch_bounds__(256) void rgcn_gather_basis(const int* __restrict__ rowptr,
                                                         const int* __restrict__ elist,
                                                         const float* __restrict__ basis,
                                                         const float* __restrict__ comp,
                                                         const float* __restrict__ root,
                                                         const float* __restrict__ bias,
                                                         unsigned short* __restrict__ dbf_h) {
    int wid  = blockIdx.x * 4 + (threadIdx.x >> 6);
    int lane = threadIdx.x & 63;
    if (wid >= N_ENT) return;
    int beg = rowptr[wid], end = rowptr[wid + 1];
    float a0 = 0.f, a1 = 0.f;
    for (int p = beg; p < end; ++p) {
        int v = elist[p];
        int src = v & 0x3FFFF, ty = v >> 18;
        const float* c = comp + ty * NBASIS;
#pragma unroll
        for (int b = 0; b < NBASIS; ++b) {
            const float* bp = basis + ((size_t)b * N_ENT + src) * DIM;
            a0 += c[b] * bp[lane * 2];
            a1 += c[b] * bp[lane * 2 + 1];
        }
    }
    float inv = 1.f / fmaxf((float)(end - beg), 1.f);
    size_t base = (size_t)wid * DIM + lane * 2;
    float f0 = a0 * inv + root[base]     + bias[lane * 2];
    float f1 = a1 * inv + root[base + 1] + bias[lane * 2 + 1];
    *(unsigned int*)(dbf_h + base) = (unsigned int)f2bf(f0) | ((unsigned int)f2bf(f1) << 16);
}

// shared escore body: e[n] = sum_d v[d] * tanh( (feats[n,:] @ A)[d] ) for 32 rows at m0
__device__ __forceinline__ void escore_body(const unsigned short* __restrict__ feats,
                                            const unsigned short* __restrict__ At,
                                            const float* __restrict__ v,
                                            float* __restrict__ eo,
                                            int m0, int nrow) {
    __shared__ float part[4][32];
    int t = threadIdx.x;
    int wave = t >> 6, lane = t & 63;
    int n0 = wave * 32;                 // 4 waves cover all 128 output dims
    int am = lane & 31, ak = (lane >> 5) * 8;
    int mrow = m0 + am;
    bool mv = mrow < nrow;
    const unsigned short* Ar = feats + (size_t)mrow * DIM + ak;
    const unsigned short* Br = At + (size_t)(n0 + am) * DIM + ak;
    facc16 acc;
#pragma unroll
    for (int r = 0; r < 16; ++r) acc[r] = 0.f;
#pragma unroll
    for (int s = 0; s < 8; ++s) {
        bfrag8 a;
#pragma unroll
        for (int j = 0; j < 8; ++j) a[j] = 0;
        if (mv) a = *(const bfrag8*)(Ar + s * 16);
        bfrag8 b = *(const bfrag8*)(Br + s * 16);
        acc = __builtin_amdgcn_mfma_f32_32x32x16_bf16(a, b, acc, 0, 0, 0);
    }
    int col = lane & 31, g = lane >> 5;
    float vn = v[n0 + col];
#pragma unroll
    for (int r = 0; r < 16; ++r) {
        float x = tanhf(acc[r]) * vn;
#pragma unroll
        for (int off = 16; off >= 1; off >>= 1) x += __shfl_xor(x, off, 32);
        if (col == 0) {
            int row = (r & 3) + ((r >> 2) << 3) + (g << 2);
            part[wave][row] = x;
        }
    }
    __syncthreads();
    if (t < 32) {
        int m = m0 + t;
        if (m < nrow)
            eo[m] = part[0][t] + part[1][t] + part[2][t] + part[3][t];
    }
}

// ============================ dispatch 5: db escore (x) con escore — parity-interleaved
__global__ __launch_bounds__(256) void escores_kernel(const unsigned short* __restrict__ dbf_h,
                                                      const unsigned short* __restrict__ At_db_h,
                                                      const float* __restrict__ v_db,
                                                      float* __restrict__ e_db,
                                                      const unsigned short* __restrict__ conf_h,
                                                      const unsigned short* __restrict__ At_c_h,
                                                      const float* __restrict__ v_c,
                                                      float* __restrict__ e_con) {
    int bb = blockIdx.x;
    int pair = bb >> 1;
    if ((bb & 1) == 0) {
        if (pair >= NB_EDB) return;
        escore_body(dbf_h, At_db_h, v_db, e_db, pair * 32, N_ENT);
    } else {
        if (pair >= NB_ECON) return;
        escore_body(conf_h, At_c_h, v_c, e_con, pair * 32, N_CON);
    }
}

// ============================ dispatch 6: softmax + weighted sums + gated fusion per sample
__global__ __launch_bounds__(256) void attn_fusion_kernel(const unsigned short* __restrict__ dbf_h,
                                                          const unsigned short* __restrict__ conf_h,
                                                          const float* __restrict__ e_db,
                                                          const float* __restrict__ e_con,
                                                          const int* __restrict__ seed_pad,
                                                          const int* __restrict__ seed_lens,
                                                          const int* __restrict__ concept_mask,
                                                          const float* __restrict__ Wu, const float* __restrict__ bu,
                                                          const float* __restrict__ gw, const float* __restrict__ gb,
                                                          const float* __restrict__ Wi, const float* __restrict__ bi,
                                                          unsigned short* __restrict__ uemb_h,
                                                          unsigned short* __restrict__ cone_h,
                                                          float* __restrict__ maskv) {
    __shared__ int srow[SSEED];
    __shared__ int crow[LCON];
    __shared__ float a_db[SSEED], a_con[LCON];
    __shared__ float du[DIM], cu[DIM], red[DIM];
    int b = blockIdx.x, t = threadIdx.x;
    int wave = t >> 6, lane = t & 63;
    int len = seed_lens[b];
    if (wave == 0) {
        // db softmax over S=32 (lanes 0..31)
        float e = -1e30f;
        if (lane < SSEED) {
            int rv = seed_pad[b * SSEED + lane];
            srow[lane] = rv;
            if (lane < len) e = e_db[rv];
        }
        float m = e;
#pragma unroll
        for (int off = 16; off >= 1; off >>= 1) m = fmaxf(m, __shfl_xor(m, off, 32));
        float p = (lane < SSEED) ? __expf(e - m) : 0.f;
        float s = p;
#pragma unroll
        for (int off = 16; off >= 1; off >>= 1) s += __shfl_xor(s, off, 32);
        if (lane < SSEED) a_db[lane] = p / s;
    } else if (wave == 1) {
        // con softmax over LC=50 (lanes 0..49)
        float e = -1e30f;
        if (lane < LCON) {
            int rv = concept_mask[b * LCON + lane];
            crow[lane] = rv;
            if (rv != 0) e = e_con[rv];
        }
        float m = e;
#pragma unroll
        for (int off = 32; off >= 1; off >>= 1) m = fmaxf(m, __shfl_xor(m, off, 64));
        float p = (lane < LCON) ? __expf(e - m) : 0.f;
        float s = p;
#pragma unroll
        for (int off = 32; off >= 1; off >>= 1) s += __shfl_xor(s, off, 64);
        if (lane < LCON) a_con[lane] = p / s;
    }
    __syncthreads();
    // weighted row sums: threads 0..127 -> du, 128..255 -> cu
    if (t < DIM) {
        float acc = 0.f;
#pragma unroll
        for (int s = 0; s < SSEED; ++s)
            acc += a_db[s] * bf2f((unsigned int)dbf_h[(size_t)srow[s] * DIM + t]);
        du[t] = (len > 0) ? acc : 0.f;
    } else {
        int d = t - DIM;
        float acc = 0.f;
#pragma unroll
        for (int s = 0; s < LCON; ++s)
            acc += a_con[s] * bf2f((unsigned int)conf_h[(size_t)crow[s] * DIM + d]);
        cu[d] = acc;
    }
    __syncthreads();
    // fusion
    if (t < DIM) {
        float u = bu[t];
        const float* wr = Wu + t * 2 * DIM;
        for (int k = 0; k < DIM; ++k) u += cu[k] * wr[k];
        for (int k = 0; k < DIM; ++k) u += du[k] * wr[DIM + k];
        red[t] = u * gw[t];
    }
    __syncthreads();
    for (int s2 = 64; s2 > 0; s2 >>= 1) {
        if (t < s2) red[t] += red[t + s2];
        __syncthreads();
    }
    if (t < DIM) {
        float gate = 1.f / (1.f + __expf(-(red[0] + gb[0])));
        uemb_h[b * DIM + t] = f2bf(gate * du[t] + (1.f - gate) * cu[t]);
        float ce = bi[t];
        const float* wi = Wi + t * DIM;
        for (int k = 0; k < DIM; ++k) ce += cu[k] * wi[k];
        cone_h[b * DIM + t] = f2bf(ce);
    }
    if (t == 0) maskv[b] = (len > 0) ? 1.f : 0.f;
}

// ============================ dispatch 7: fused scoring GEMMs (MFMA) + CE/ssq partials
__global__ __launch_bounds__(256) void score_mfma(const unsigned short* __restrict__ dbf_h,
                                                  const unsigned short* __restrict__ uemb_h,
                                                  const unsigned short* __restrict__ cone_h,
                                                  const float* __restrict__ en_b,
                                                  const float* __restrict__ info_b,
                                                  const float* __restrict__ db_vec,
                                                  float* __restrict__ escore,
                                                  float* __restrict__ partM,
                                                  float* __restrict__ partS,
                                                  float* __restrict__ partQ) {
    int wave = threadIdx.x >> 6, lane = threadIdx.x & 63;
    int nt = blockIdx.x * 4 + wave;
    if (nt >= NTILE) return;
    int b0 = blockIdx.y * 32;
    int n0 = nt * 32;
    int am = lane & 31, ak = (lane >> 5) * 8;
    int nb = n0 + am;
    bool bvalid = nb < N_ENT;
    const unsigned short* Au = uemb_h + (size_t)(b0 + am) * DIM + ak;
    const unsigned short* Ac = cone_h + (size_t)(b0 + am) * DIM + ak;
    const unsigned short* Bp = dbf_h + (size_t)nb * DIM + ak;
    facc16 accE, accD;
#pragma unroll
    for (int r = 0; r < 16; ++r) { accE[r] = 0.f; accD[r] = 0.f; }
#pragma unroll
    for (int s = 0; s < 8; ++s) {
        bfrag8 au = *(const bfrag8*)(Au + s * 16);
        bfrag8 ac = *(const bfrag8*)(Ac + s * 16);
        bfrag8 bb;
#pragma unroll
        for (int j = 0; j < 8; ++j) bb[j] = 0;
        if (bvalid) bb = *(const bfrag8*)(Bp + s * 16);
        accE = __builtin_amdgcn_mfma_f32_32x32x16_bf16(au, bb, accE, 0, 0, 0);
        accD = __builtin_amdgcn_mfma_f32_32x32x16_bf16(ac, bb, accD, 0, 0, 0);
    }
    int col = lane & 31;
    int n = n0 + col;
    bool nv = n < N_ENT;
    float enb = nv ? en_b[n] : 0.f;
    float inb = nv ? info_b[n] : 0.f;
    int g4 = (lane >> 5) * 4;
#pragma unroll
    for (int r = 0; r < 16; ++r) {
        int b = b0 + (r & 3) + ((r >> 2) << 3) + g4;
        float e = accE[r] + enb;
        if (nv) escore[(size_t)b * N_ENT + n] = e;
        float ev = nv ? e : -1e30f;
        float mx = ev;
#pragma unroll
        for (int off = 16; off >= 1; off >>= 1) mx = fmaxf(mx, __shfl_xor(mx, off, 64));
        float ex = nv ? __expf(e - mx) : 0.f;
        float sm = ex;
#pragma unroll
        for (int off = 16; off >= 1; off >>= 1) sm += __shfl_xor(sm, off, 64);
        float d = nv ? (accD[r] + inb - db_vec[(size_t)b * N_ENT + n]) : 0.f;
        float q = d * d;
#pragma unroll
        for (int off = 16; off >= 1; off >>= 1) q += __shfl_xor(q, off, 64);
        if (col == 0) {
            partM[(size_t)b * NTILE + nt] = mx;
            partS[(size_t)b * NTILE + nt] = sm;
            partQ[(size_t)b * NTILE + nt] = q;
        }
    }
}

// ============================ dispatch 8: CE finalize from partials
__global__ __launch_bounds__(256) void ce_final(const float* __restrict__ partM,
                                                const float* __restrict__ partS,
                                                const float* __restrict__ partQ,
                                                const float* __restrict__ escore,
                                                const int* __restrict__ labels,
                                                const float* __restrict__ rec,
                                                float* __restrict__ rloss,
                                                float* __restrict__ ssqv) {
    __shared__ float red[256], red2[256];
    int b = blockIdx.x, t = threadIdx.x;
    const float* pm = partM + (size_t)b * NTILE;
    const float* ps = partS + (size_t)b * NTILE;
    const float* pq = partQ + (size_t)b * NTILE;
    float mx = -1e30f;
    for (int i = t; i < NTILE; i += 256) mx = fmaxf(mx, pm[i]);
    red[t] = mx;
    __syncthreads();
    for (int s2 = 128; s2 > 0; s2 >>= 1) {
        if (t < s2) red[t] = fmaxf(red[t], red[t + s2]);
        __syncthreads();
    }
    float M = red[0];
    __syncthreads();
    float s = 0.f, q = 0.f;
    for (int i = t; i < NTILE; i += 256) {
        s += ps[i] * __expf(pm[i] - M);
        q += pq[i];
    }
    red[t] = s; red2[t] = q;
    __syncthreads();
    for (int s2 = 128; s2 > 0; s2 >>= 1) {
        if (t < s2) { red[t] += red[t + s2]; red2[t] += red2[t + s2]; }
        __syncthreads();
    }
    if (t == 0) {
        float lse = M + logf(red[0]);
        float ce  = -(escore[(size_t)b * N_ENT + labels[b]] - lse);
        rloss[b]  = ce * rec[b];
        ssqv[b]   = red2[0];
    }
}

// ============================ dispatch 9: final scalar reduction
__global__ __launch_bounds__(256) void final_kernel(const float* __restrict__ rloss,
                                                    const float* __restrict__ sumsq,
                                                    const float* __restrict__ maskv,
                                                    float* __restrict__ out) {
    __shared__ float r1[256], r2[256];
    int t = threadIdx.x;
    r1[t] = rloss[t];
    r2[t] = sumsq[t] * maskv[t];
    __syncthreads();
    for (int s2 = 128; s2 > 0; s2 >>= 1) {
        if (t < s2) { r1[t] += r1[t + s2]; r2[t] += r2[t + s2]; }
        __syncthreads();
    }
    if (t == 0) {
        float rec_loss = r1[0];
        float info = r2[0] / (float)BATCH;
        out[0] = rec_loss + 0.025f * info;
        out[1 + (size_t)BATCH * N_ENT] = rec_loss;
    }
}

// ============================ launch
extern "C" void kernel_launch(void* const* d_in, const int* in_sizes, int n_in,
                              void* d_out, int out_size, void* d_ws, size_t ws_size,
                              hipStream_t stream) {
    (void)in_sizes; (void)n_in; (void)out_size;
    const int*   concept_mask  = (const int*)d_in[0];
    const int*   seed_pad      = (const int*)d_in[1];
    const int*   seed_lens     = (const int*)d_in[2];
    const int*   db_eidx       = (const int*)d_in[3];
    const int*   db_etype      = (const int*)d_in[4];
    const int*   con_eidx      = (const int*)d_in[5];
    const float* db_vec        = (const float*)d_in[6];
    const int*   labels        = (const int*)d_in[7];
    const float* rec           = (const float*)d_in[8];
    const float* concept_emb   = (const float*)d_in[9];
    const float* basis         = (const float*)d_in[10];
    const float* comp          = (const float*)d_in[11];
    const float* rgcn_root     = (const float*)d_in[12];
    const float* rgcn_bias     = (const float*)d_in[13];
    const float* gcn_w         = (const float*)d_in[14];
    const float* gcn_b         = (const float*)d_in[15];
    const float* attn_a        = (const float*)d_in[16];
    const float* attn_b        = (const float*)d_in[17];
    const float* attn_a_db     = (const float*)d_in[18];
    const float* attn_b_db     = (const float*)d_in[19];
    const float* user_norm_w   = (const float*)d_in[20];
    const float* user_norm_b   = (const float*)d_in[21];
    const float* gate_norm_w   = (const float*)d_in[22];
    const float* gate_norm_b   = (const float*)d_in[23];
    const float* info_con_w    = (const float*)d_in[24];
    const float* info_con_b    = (const float*)d_in[25];
    const float* info_out_db_b = (const float*)d_in[26];
    const float* output_en_b   = (const float*)d_in[27];

    float* ws = (float*)d_ws;
    size_t off = 0;
    auto alloc = [&](size_t n) { float* p = ws + off; off += (n + 255) & ~(size_t)255; return p; };
    float* dinv   = alloc(N_CON);
    float* maskv  = alloc(BATCH);
    float* rls    = alloc(BATCH);
    float* ssqv   = alloc(BATCH);
    float* partM  = alloc((size_t)BATCH * NTILE);
    float* partS  = alloc((size_t)BATCH * NTILE);
    float* partQ  = alloc((size_t)BATCH * NTILE);
    int* cnt_e    = (int*)alloc(N_ENT + N_CON);     // contiguous for one memset
    int* cnt_c    = cnt_e + N_ENT;
    int* rowptr_e = (int*)alloc(N_ENT + 1);
    int* rowptr_c = (int*)alloc(N_CON + 1);
    int* ord_db   = (int*)alloc(EDB);
    int* ord_con  = (int*)alloc(ECON);
    int* elist_e  = (int*)alloc(EDB);
    int* elist_c  = (int*)alloc(ECON);
    unsigned short* dbf_h  = (unsigned short*)alloc((size_t)N_ENT * DIM / 2);
    unsigned short* conf_h = (unsigned short*)alloc((size_t)N_CON * DIM / 2 + 128);
    unsigned short* xw_h   = (unsigned short*)alloc((size_t)N_CON * DIM / 2 + 128);
    unsigned short* emb_h  = (unsigned short*)alloc((size_t)N_CON * DIM / 2 + 128);
    unsigned short* Wt_h   = (unsigned short*)alloc(DIM * DIM / 2);
    unsigned short* uemb_h = (unsigned short*)alloc(BATCH * DIM / 2);
    unsigned short* cone_h = (unsigned short*)alloc(BATCH * DIM / 2);
    float* e_db   = alloc(N_ENT);
    float* e_con  = alloc(N_CON);
    unsigned short* At_db_h = (unsigned short*)alloc(DIM * DIM / 2);
    unsigned short* At_c_h  = (unsigned short*)alloc(DIM * DIM / 2);
    size_t w_elems = ((size_t)NREL * N_ENT * DIM) / 2;   // bf16 in float-units
    int use_w = (off + w_elems) * sizeof(float) <= ws_size;
    unsigned short* w_h = (unsigned short*)(ws + off);

    float* out    = (float*)d_out;
    float* escore = out + 1;

    (void)hipMemsetAsync(cnt_e, 0, (N_ENT + N_CON) * sizeof(int), stream);

    prep_kernel<<<NB_PREP, 256, 0, stream>>>(
        db_eidx + EDB, con_eidx + ECON, concept_emb, gcn_w, attn_a_db, attn_a,
        basis, comp, cnt_e, cnt_c, ord_db, ord_con, emb_h, Wt_h, At_db_h, At_c_h,
        w_h, use_w);
    scan2_kernel<<<2 + NB_XW, 1024, 0, stream>>>(cnt_e, cnt_c, rowptr_e, rowptr_c, dinv,
                                                 emb_h, Wt_h, xw_h);
    scatter_kernel<<<NB_HIST, 256, 0, stream>>>(db_eidx, db_etype, con_eidx,
                                                ord_db, ord_con, rowptr_e, rowptr_c,
                                                elist_e, elist_c);
    gathers_kernel<<<NB_RG * 2, 256, 0, stream>>>(rowptr_e, elist_e, w_h, rgcn_root, rgcn_bias,
                                                  dbf_h, rowptr_c, elist_c, dinv, xw_h, gcn_b,
                                                  conf_h, use_w);
    if (!use_w) {
        rgcn_gather_basis<<<NB_RG, 256, 0, stream>>>(rowptr_e, elist_e, basis, comp,
                                                     rgcn_root, rgcn_bias, dbf_h);
    }
    escores_kernel<<<NB_EDB * 2, 256, 0, stream>>>(dbf_h, At_db_h, attn_b_db, e_db,
                                                   conf_h, At_c_h, attn_b, e_con);
    attn_fusion_kernel<<<BATCH, 256, 0, stream>>>(dbf_h, conf_h, e_db, e_con,
                                                  seed_pad, seed_lens, concept_mask,
                                                  user_norm_w, user_norm_b, gate_norm_w, gate_norm_b,
                                                  info_con_w, info_con_b, uemb_h, cone_h, maskv);
    dim3 sg((NTILE + 3) / 4, BATCH / 32);
    score_mfma<<<sg, 256, 0, stream>>>(dbf_h, uemb_h, cone_h, output_en_b, info_out_db_b, db_vec,
                                       escore, partM, partS, partQ);
    ce_final<<<BATCH, 256, 0, stream>>>(partM, partS, partQ, escore, labels, rec, rls, ssqv);
    final_kernel<<<1, 256, 0, stream>>>(rls, ssqv, maskv, out);
}

// Round 5
// 503.989 us; speedup vs baseline: 1.1739x; 1.0057x over previous
//
#include <hip/hip_runtime.h>

#define N_ENT  30000
#define N_CON  29309
#define DIM    128
#define NBASIS 8
#define NREL   12
#define BATCH  256
#define LCON   50
#define SSEED  32
#define EDB    300000
#define ECON   200000
#define NTILE  938   // ceil(N_ENT/32)

#define NE4      ((N_CON * DIM) / 4)          // 937888 (exact)
#define NB_HIST  ((EDB + ECON + 255) / 256)   // 1954
// conv items (float4 units): emb NE4 + 3 bf16 mats 12288 + WuT 8192 + WiT 4096
#define NB_CONV  ((NE4 + 24576 + 255) / 256)  // 3760
#define NB_WCOMP ((N_ENT * 32) / 256)         // 3750
#define NB_PREP  (NB_HIST * 5)                // 9770: slot0=hist, slot1/2=conv, slot3/4=wcomp
#define NB_XW    ((N_CON + 127) / 128)        // 229 (1024-thread blocks, 128 rows each)
#define NB_RG    ((N_ENT + 3) / 4)            // 7500 (fallback kernel)
#define NB_RG8   ((N_ENT + 7) / 8)            // 3750
#define NB_GG8   ((N_CON + 7) / 8)            // 3664
#define NB_EDB   ((N_ENT + 31) / 32)          // 938
#define NB_ECON  ((N_CON + 31) / 32)          // 916

typedef __attribute__((ext_vector_type(8)))  short bfrag8;
typedef __attribute__((ext_vector_type(16))) float facc16;

__device__ __forceinline__ unsigned short f2bf(float f) {
    unsigned int u = __float_as_uint(f);
    u += 0x7FFFu + ((u >> 16) & 1u);
    return (unsigned short)(u >> 16);
}
__device__ __forceinline__ float bf2f(unsigned int h) {
    return __uint_as_float(h << 16);
}
__device__ __forceinline__ unsigned int pk(float a, float b) {
    return (unsigned int)f2bf(a) | ((unsigned int)f2bf(b) << 16);
}

// ============================ dispatch 1: hist (x) conv (x) wcomp — modulo-interleaved roles
__global__ __launch_bounds__(256) void prep_kernel(const int* __restrict__ db_dst,
                                                   const int* __restrict__ con_dst,
                                                   const float* __restrict__ emb,
                                                   const float* __restrict__ W,
                                                   const float* __restrict__ A_db,
                                                   const float* __restrict__ A_c,
                                                   const float* __restrict__ Wu,
                                                   const float* __restrict__ Wi,
                                                   const float* __restrict__ basis,
                                                   const float* __restrict__ comp,
                                                   int* __restrict__ cnt_e, int* __restrict__ cnt_c,
                                                   int* __restrict__ ord_db, int* __restrict__ ord_con,
                                                   unsigned short* __restrict__ emb_h,
                                                   unsigned short* __restrict__ Wt_h,
                                                   unsigned short* __restrict__ At_db_h,
                                                   unsigned short* __restrict__ At_c_h,
                                                   float* __restrict__ WuT,
                                                   float* __restrict__ WiT,
                                                   unsigned short* __restrict__ w_h,
                                                   int use_w) {
    __shared__ float sc[NREL * NBASIS];
    int t = threadIdx.x, bb = blockIdx.x;
    int g = bb / 5, slot = bb % 5;
    if (slot == 0) {
        // ---- histogram with ordinals (g < NB_HIST by construction)
        int e = g * 256 + t;
        if (e < EDB) {
            ord_db[e] = atomicAdd(cnt_e + db_dst[e], 1);
        } else if (e < EDB + ECON) {
            int ee = e - EDB;
            ord_con[ee] = atomicAdd(cnt_c + con_dst[ee], 1);
        }
        return;
    }
    if (slot <= 2) {
        // ---- bf16 conversions + fp32 transposes
        int cb = g * 2 + (slot - 1);
        if (cb >= NB_CONV) return;
        int i = cb * 256 + t;
        if (i < NE4) {
            float4 v = ((const float4*)emb)[i];
            *(uint2*)(emb_h + (size_t)i * 4) = make_uint2(pk(v.x, v.y), pk(v.z, v.w));
            return;
        }
        int j = i - NE4;
        if (j < 12288) {
            int sel = j >> 12;             // DIM*DIM/4 = 4096 = 1<<12
            int jj = j & 4095;
            const float* S = (sel == 0) ? W : ((sel == 1) ? A_db : A_c);
            unsigned short* Dst = (sel == 0) ? Wt_h : ((sel == 1) ? At_db_h : At_c_h);
            int o = jj * 4;
            int n = o >> 7, k0 = o & 127;
            unsigned int p0 = pk(S[(k0 + 0) * DIM + n], S[(k0 + 1) * DIM + n]);
            unsigned int p1 = pk(S[(k0 + 2) * DIM + n], S[(k0 + 3) * DIM + n]);
            *(uint2*)(Dst + n * DIM + k0) = make_uint2(p0, p1);
            return;
        }
        int j2 = j - 12288;
        if (j2 < 8192) {
            // WuT[k][t] = Wu[t][k], k<256, t<128 (fp32)
            int o = j2 * 4;
            int k = o >> 7, t0 = o & 127;
            float4 vv;
            vv.x = Wu[(t0 + 0) * (2 * DIM) + k];
            vv.y = Wu[(t0 + 1) * (2 * DIM) + k];
            vv.z = Wu[(t0 + 2) * (2 * DIM) + k];
            vv.w = Wu[(t0 + 3) * (2 * DIM) + k];
            *(float4*)(WuT + k * DIM + t0) = vv;
            return;
        }
        int j3 = j2 - 8192;
        if (j3 < 4096) {
            // WiT[k][t] = Wi[t][k], k<128, t<128 (fp32)
            int o = j3 * 4;
            int k = o >> 7, t0 = o & 127;
            float4 vv;
            vv.x = Wi[(t0 + 0) * DIM + k];
            vv.y = Wi[(t0 + 1) * DIM + k];
            vv.z = Wi[(t0 + 2) * DIM + k];
            vv.w = Wi[(t0 + 3) * DIM + k];
            *(float4*)(WiT + k * DIM + t0) = vv;
        }
        return;
    }
    // ---- wcomp: w_h[n][r][:] = bf16(sum_b comp[r,b]*basis[b,n,:])
    if (!use_w) return;
    int wb = g * 2 + (slot - 3);
    if (wb >= NB_WCOMP) return;
    if (t < NREL * NBASIS) sc[t] = comp[t];
    __syncthreads();
    int i = wb * 256 + t;
    int n = i >> 5, d4 = i & 31;
    float4 bv[NBASIS];
#pragma unroll
    for (int b = 0; b < NBASIS; ++b)
        bv[b] = ((const float4*)(basis + ((size_t)b * N_ENT + n) * DIM))[d4];
#pragma unroll
    for (int r = 0; r < NREL; ++r) {
        float4 acc = make_float4(0.f, 0.f, 0.f, 0.f);
#pragma unroll
        for (int b = 0; b < NBASIS; ++b) {
            float c = sc[r * NBASIS + b];
            acc.x += c * bv[b].x; acc.y += c * bv[b].y;
            acc.z += c * bv[b].z; acc.w += c * bv[b].w;
        }
        *(uint2*)(w_h + ((size_t)n * NREL + r) * DIM + d4 * 4) =
            make_uint2(pk(acc.x, acc.y), pk(acc.z, acc.w));
    }
}

// ============================ dispatch 2: two exclusive scans (+dinv) + xw MFMA filling idle CUs
__device__ void scan_block(const int* __restrict__ cnt, int n, int* __restrict__ rowptr) {
    __shared__ int part[1024];
    int t = threadIdx.x;
    int per = (n + 1023) / 1024;
    int s0 = t * per;
    int sum = 0;
    for (int i = 0; i < per; ++i) {
        int idx = s0 + i;
        if (idx < n) sum += cnt[idx];
    }
    part[t] = sum;
    __syncthreads();
    for (int off = 1; off < 1024; off <<= 1) {
        int v = (t >= off) ? part[t - off] : 0;
        __syncthreads();
        part[t] += v;
        __syncthreads();
    }
    int run = part[t] - sum;
    for (int i = 0; i < per; ++i) {
        int idx = s0 + i;
        if (idx < n) {
            rowptr[idx] = run;
            run += cnt[idx];
        }
    }
    if (t == 1023) rowptr[n] = part[1023];
}

__global__ __launch_bounds__(1024) void scan2_kernel(const int* __restrict__ cnt_e,
                                                     const int* __restrict__ cnt_c,
                                                     int* __restrict__ rowptr_e,
                                                     int* __restrict__ rowptr_c,
                                                     float* __restrict__ dinv,
                                                     const unsigned short* __restrict__ emb_h,
                                                     const unsigned short* __restrict__ Wt_h,
                                                     unsigned short* __restrict__ xw_h) {
    int bb = blockIdx.x;
    if (bb == 0) {
        scan_block(cnt_e, N_ENT, rowptr_e);
        return;
    }
    if (bb == 1) {
        scan_block(cnt_c, N_CON, rowptr_c);
        for (int i = threadIdx.x; i < N_CON; i += 1024)
            dinv[i] = rsqrtf((float)(cnt_c[i] + 1));
        return;
    }
    // ---- xw_h = bf16(emb @ W) via MFMA; 16 waves cover 128 rows x 128 cols
    int t = threadIdx.x;
    int wave = t >> 6, lane = t & 63;
    int m0 = (bb - 2) * 128 + (wave >> 2) * 32;
    int n0 = (wave & 3) * 32;
    int am = lane & 31, ak = (lane >> 5) * 8;
    int mrow = m0 + am;
    bool mv = mrow < N_CON;
    const unsigned short* Ar = emb_h + (size_t)mrow * DIM + ak;
    const unsigned short* Br = Wt_h + (size_t)(n0 + am) * DIM + ak;
    facc16 acc;
#pragma unroll
    for (int r = 0; r < 16; ++r) acc[r] = 0.f;
#pragma unroll
    for (int s = 0; s < 8; ++s) {
        bfrag8 a;
#pragma unroll
        for (int j = 0; j < 8; ++j) a[j] = 0;
        if (mv) a = *(const bfrag8*)(Ar + s * 16);
        bfrag8 b = *(const bfrag8*)(Br + s * 16);
        acc = __builtin_amdgcn_mfma_f32_32x32x16_bf16(a, b, acc, 0, 0, 0);
    }
    int col = lane & 31;
    int g4 = (lane >> 5) * 4;
#pragma unroll
    for (int r = 0; r < 16; ++r) {
        int m = m0 + (r & 3) + ((r >> 2) << 3) + g4;
        if (m < N_CON) xw_h[(size_t)m * DIM + n0 + col] = f2bf(acc[r]);
    }
}

// ============================ dispatch 3: scatter only (pure writes, ordinals precomputed)
__global__ __launch_bounds__(256) void scatter_kernel(const int* __restrict__ db_eidx,
                                                      const int* __restrict__ db_etype,
                                                      const int* __restrict__ con_eidx,
                                                      const int* __restrict__ ord_db,
                                                      const int* __restrict__ ord_con,
                                                      const int* __restrict__ rowptr_e,
                                                      const int* __restrict__ rowptr_c,
                                                      int* __restrict__ elist_e,
                                                      int* __restrict__ elist_c) {
    int e = blockIdx.x * 256 + threadIdx.x;
    if (e < EDB) {
        int dst = db_eidx[EDB + e];
        elist_e[rowptr_e[dst] + ord_db[e]] = db_eidx[e] | (db_etype[e] << 18);
    } else if (e < EDB + ECON) {
        int ee = e - EDB;
        int dst = con_eidx[ECON + ee];
        elist_c[rowptr_c[dst] + ord_con[ee]] = con_eidx[ee];
    }
}

// ============================ dispatch 4: RGCN (x) GCN gathers — one row per 32-lane half-wave
__global__ __launch_bounds__(256) void gathers_kernel(const int* __restrict__ rowptr_e,
                                                      const int* __restrict__ elist_e,
                                                      const unsigned short* __restrict__ w_h,
                                                      const float* __restrict__ root,
                                                      const float* __restrict__ bias,
                                                      unsigned short* __restrict__ dbf_h,
                                                      const int* __restrict__ rowptr_c,
                                                      const int* __restrict__ elist_c,
                                                      const float* __restrict__ dinv,
                                                      const unsigned short* __restrict__ xw_h,
                                                      const float* __restrict__ gcn_b,
                                                      unsigned short* __restrict__ conf_h,
                                                      int use_w) {
    int bb = blockIdx.x;
    int pair = bb >> 1;
    int half = threadIdx.x >> 5;   // 8 rows per block
    int lane = threadIdx.x & 31;   // 4 dims per lane (8 B)
    if ((bb & 1) == 0) {
        // ---- RGCN gather (pair < 3750, wid < 30000 exact)
        if (!use_w) return;
        int wid = pair * 8 + half;
        int beg = rowptr_e[wid], end = rowptr_e[wid + 1];
        float a0 = 0.f, a1 = 0.f, a2 = 0.f, a3 = 0.f;
        int p = beg;
        for (; p + 3 < end; p += 4) {
            int v0 = elist_e[p], v1 = elist_e[p + 1], v2 = elist_e[p + 2], v3 = elist_e[p + 3];
            uint2 k0 = *(const uint2*)(w_h + ((size_t)(v0 & 0x3FFFF) * NREL + (v0 >> 18)) * DIM + lane * 4);
            uint2 k1 = *(const uint2*)(w_h + ((size_t)(v1 & 0x3FFFF) * NREL + (v1 >> 18)) * DIM + lane * 4);
            uint2 k2 = *(const uint2*)(w_h + ((size_t)(v2 & 0x3FFFF) * NREL + (v2 >> 18)) * DIM + lane * 4);
            uint2 k3 = *(const uint2*)(w_h + ((size_t)(v3 & 0x3FFFF) * NREL + (v3 >> 18)) * DIM + lane * 4);
            a0 += bf2f(k0.x & 0xFFFF) + bf2f(k1.x & 0xFFFF) + bf2f(k2.x & 0xFFFF) + bf2f(k3.x & 0xFFFF);
            a1 += bf2f(k0.x >> 16)    + bf2f(k1.x >> 16)    + bf2f(k2.x >> 16)    + bf2f(k3.x >> 16);
            a2 += bf2f(k0.y & 0xFFFF) + bf2f(k1.y & 0xFFFF) + bf2f(k2.y & 0xFFFF) + bf2f(k3.y & 0xFFFF);
            a3 += bf2f(k0.y >> 16)    + bf2f(k1.y >> 16)    + bf2f(k2.y >> 16)    + bf2f(k3.y >> 16);
        }
        for (; p < end; ++p) {
            int v = elist_e[p];
            uint2 k = *(const uint2*)(w_h + ((size_t)(v & 0x3FFFF) * NREL + (v >> 18)) * DIM + lane * 4);
            a0 += bf2f(k.x & 0xFFFF);
            a1 += bf2f(k.x >> 16);
            a2 += bf2f(k.y & 0xFFFF);
            a3 += bf2f(k.y >> 16);
        }
        float inv = 1.f / fmaxf((float)(end - beg), 1.f);
        size_t base = (size_t)wid * DIM + lane * 4;
        int d0 = lane * 4;
        float f0 = a0 * inv + root[base]     + bias[d0];
        float f1 = a1 * inv + root[base + 1] + bias[d0 + 1];
        float f2 = a2 * inv + root[base + 2] + bias[d0 + 2];
        float f3 = a3 * inv + root[base + 3] + bias[d0 + 3];
        *(uint2*)(dbf_h + base) = make_uint2(pk(f0, f1), pk(f2, f3));
        return;
    }
    // ---- GCN gather
    if (pair >= NB_GG8) return;
    int wid = pair * 8 + half;
    if (wid >= N_CON) return;
    int beg = rowptr_c[wid], end = rowptr_c[wid + 1];
    float a0 = 0.f, a1 = 0.f, a2 = 0.f, a3 = 0.f;
    int p = beg;
    for (; p + 3 < end; p += 4) {
        int s0 = elist_c[p], s1 = elist_c[p + 1], s2 = elist_c[p + 2], s3 = elist_c[p + 3];
        float n0 = dinv[s0], n1 = dinv[s1], n2 = dinv[s2], n3 = dinv[s3];
        uint2 k0 = *(const uint2*)(xw_h + (size_t)s0 * DIM + lane * 4);
        uint2 k1 = *(const uint2*)(xw_h + (size_t)s1 * DIM + lane * 4);
        uint2 k2 = *(const uint2*)(xw_h + (size_t)s2 * DIM + lane * 4);
        uint2 k3 = *(const uint2*)(xw_h + (size_t)s3 * DIM + lane * 4);
        a0 += n0 * bf2f(k0.x & 0xFFFF) + n1 * bf2f(k1.x & 0xFFFF) + n2 * bf2f(k2.x & 0xFFFF) + n3 * bf2f(k3.x & 0xFFFF);
        a1 += n0 * bf2f(k0.x >> 16)    + n1 * bf2f(k1.x >> 16)    + n2 * bf2f(k2.x >> 16)    + n3 * bf2f(k3.x >> 16);
        a2 += n0 * bf2f(k0.y & 0xFFFF) + n1 * bf2f(k1.y & 0xFFFF) + n2 * bf2f(k2.y & 0xFFFF) + n3 * bf2f(k3.y & 0xFFFF);
        a3 += n0 * bf2f(k0.y >> 16)    + n1 * bf2f(k1.y >> 16)    + n2 * bf2f(k2.y >> 16)    + n3 * bf2f(k3.y >> 16);
    }
    for (; p < end; ++p) {
        int s = elist_c[p];
        float nm = dinv[s];
        uint2 k = *(const uint2*)(xw_h + (size_t)s * DIM + lane * 4);
        a0 += nm * bf2f(k.x & 0xFFFF);
        a1 += nm * bf2f(k.x >> 16);
        a2 += nm * bf2f(k.y & 0xFFFF);
        a3 += nm * bf2f(k.y >> 16);
    }
    float dv = dinv[wid];
    uint2 ks = *(const uint2*)(xw_h + (size_t)wid * DIM + lane * 4);
    size_t base = (size_t)wid * DIM + lane * 4;
    int d0 = lane * 4;
    float f0 = dv * a0 + dv * dv * bf2f(ks.x & 0xFFFF) + gcn_b[d0];
    float f1 = dv * a1 + dv * dv * bf2f(ks.x >> 16)    + gcn_b[d0 + 1];
    float f2 = dv * a2 + dv * dv * bf2f(ks.y & 0xFFFF) + gcn_b[d0 + 2];
    float f3 = dv * a3 + dv * dv * bf2f(ks.y >> 16)    + gcn_b[d0 + 3];
    *(uint2*)(conf_h + base) = make_uint2(pk(f0, f1), pk(f2, f3));
}

// fallback when ws too small for w_h: RGCN gather straight from fp32 basis
__global__ __launch_bounds__(256) void rgcn_gather_basis(const int* __restrict__ rowptr,
                                                         const int* __restrict__ elist,
                                                         const float* __restrict__ basis,
                                                         const float* __restrict__ comp,
                                                         const float* __restrict__ root,
                                                         const float* __restrict__ bias,
                                                         unsigned short* __restrict__ dbf_h) {
    int wid  = blockIdx.x * 4 + (threadIdx.x >> 6);
    int lane = threadIdx.x & 63;
    if (wid >= N_ENT) return;
    int beg = rowptr[wid], end = rowptr[wid + 1];
    float a0 = 0.f, a1 = 0.f;
    for (int p = beg; p < end; ++p) {
        int v = elist[p];
        int src = v & 0x3FFFF, ty = v >> 18;
        const float* c = comp + ty * NBASIS;
#pragma unroll
        for (int b = 0; b < NBASIS; ++b) {
            const float* bp = basis + ((size_t)b * N_ENT + src) * DIM;
            a0 += c[b] * bp[lane * 2];
            a1 += c[b] * bp[lane * 2 + 1];
        }
    }
    float inv = 1.f / fmaxf((float)(end - beg), 1.f);
    size_t base = (size_t)wid * DIM + lane * 2;
    float f0 = a0 * inv + root[base]     + bias[lane * 2];
    float f1 = a1 * inv + root[base + 1] + bias[lane * 2 + 1];
    *(unsigned int*)(dbf_h + base) = pk(f0, f1);
}

// shared escore body: e[n] = sum_d v[d] * tanh( (feats[n,:] @ A)[d] ) for 32 rows at m0
__device__ __forceinline__ void escore_body(const unsigned short* __restrict__ feats,
                                            const unsigned short* __restrict__ At,
                                            const float* __restrict__ v,
                                            float* __restrict__ eo,
                                            int m0, int nrow) {
    __shared__ float part[4][32];
    int t = threadIdx.x;
    int wave = t >> 6, lane = t & 63;
    int n0 = wave * 32;                 // 4 waves cover all 128 output dims
    int am = lane & 31, ak = (lane >> 5) * 8;
    int mrow = m0 + am;
    bool mv = mrow < nrow;
    const unsigned short* Ar = feats + (size_t)mrow * DIM + ak;
    const unsigned short* Br = At + (size_t)(n0 + am) * DIM + ak;
    facc16 acc;
#pragma unroll
    for (int r = 0; r < 16; ++r) acc[r] = 0.f;
#pragma unroll
    for (int s = 0; s < 8; ++s) {
        bfrag8 a;
#pragma unroll
        for (int j = 0; j < 8; ++j) a[j] = 0;
        if (mv) a = *(const bfrag8*)(Ar + s * 16);
        bfrag8 b = *(const bfrag8*)(Br + s * 16);
        acc = __builtin_amdgcn_mfma_f32_32x32x16_bf16(a, b, acc, 0, 0, 0);
    }
    int col = lane & 31, g = lane >> 5;
    float vn = v[n0 + col];
#pragma unroll
    for (int r = 0; r < 16; ++r) {
        float x = tanhf(acc[r]) * vn;
#pragma unroll
        for (int off = 16; off >= 1; off >>= 1) x += __shfl_xor(x, off, 32);
        if (col == 0) {
            int row = (r & 3) + ((r >> 2) << 3) + (g << 2);
            part[wave][row] = x;
        }
    }
    __syncthreads();
    if (t < 32) {
        int m = m0 + t;
        if (m < nrow)
            eo[m] = part[0][t] + part[1][t] + part[2][t] + part[3][t];
    }
}

// ============================ dispatch 5: db escore (x) con escore — parity-interleaved
__global__ __launch_bounds__(256) void escores_kernel(const unsigned short* __restrict__ dbf_h,
                                                      const unsigned short* __restrict__ At_db_h,
                                                      const float* __restrict__ v_db,
                                                      float* __restrict__ e_db,
                                                      const unsigned short* __restrict__ conf_h,
                                                      const unsigned short* __restrict__ At_c_h,
                                                      const float* __restrict__ v_c,
                                                      float* __restrict__ e_con) {
    int bb = blockIdx.x;
    int pair = bb >> 1;
    if ((bb & 1) == 0) {
        if (pair >= NB_EDB) return;
        escore_body(dbf_h, At_db_h, v_db, e_db, pair * 32, N_ENT);
    } else {
        if (pair >= NB_ECON) return;
        escore_body(conf_h, At_c_h, v_c, e_con, pair * 32, N_CON);
    }
}

// ============================ dispatch 6: softmax + weighted sums + gated fusion per sample
__global__ __launch_bounds__(256) void attn_fusion_kernel(const unsigned short* __restrict__ dbf_h,
                                                          const unsigned short* __restrict__ conf_h,
                                                          const float* __restrict__ e_db,
                                                          const float* __restrict__ e_con,
                                                          const int* __restrict__ seed_pad,
                                                          const int* __restrict__ seed_lens,
                                                          const int* __restrict__ concept_mask,
                                                          const float* __restrict__ WuT, const float* __restrict__ bu,
                                                          const float* __restrict__ gw, const float* __restrict__ gb,
                                                          const float* __restrict__ WiT, const float* __restrict__ bi,
                                                          unsigned short* __restrict__ uemb_h,
                                                          unsigned short* __restrict__ cone_h,
                                                          float* __restrict__ maskv) {
    __shared__ int srow[SSEED];
    __shared__ int crow[LCON];
    __shared__ float a_db[SSEED], a_con[LCON];
    __shared__ float du[DIM], cu[DIM], red[DIM];
    int b = blockIdx.x, t = threadIdx.x;
    int wave = t >> 6, lane = t & 63;
    int len = seed_lens[b];
    if (wave == 0) {
        // db softmax over S=32 (lanes 0..31)
        float e = -1e30f;
        if (lane < SSEED) {
            int rv = seed_pad[b * SSEED + lane];
            srow[lane] = rv;
            if (lane < len) e = e_db[rv];
        }
        float m = e;
#pragma unroll
        for (int off = 16; off >= 1; off >>= 1) m = fmaxf(m, __shfl_xor(m, off, 32));
        float p = (lane < SSEED) ? __expf(e - m) : 0.f;
        float s = p;
#pragma unroll
        for (int off = 16; off >= 1; off >>= 1) s += __shfl_xor(s, off, 32);
        if (lane < SSEED) a_db[lane] = p / s;
    } else if (wave == 1) {
        // con softmax over LC=50 (lanes 0..49)
        float e = -1e30f;
        if (lane < LCON) {
            int rv = concept_mask[b * LCON + lane];
            crow[lane] = rv;
            if (rv != 0) e = e_con[rv];
        }
        float m = e;
#pragma unroll
        for (int off = 32; off >= 1; off >>= 1) m = fmaxf(m, __shfl_xor(m, off, 64));
        float p = (lane < LCON) ? __expf(e - m) : 0.f;
        float s = p;
#pragma unroll
        for (int off = 32; off >= 1; off >>= 1) s += __shfl_xor(s, off, 64);
        if (lane < LCON) a_con[lane] = p / s;
    }
    __syncthreads();
    // weighted row sums: threads 0..127 -> du, 128..255 -> cu
    if (t < DIM) {
        float acc = 0.f;
#pragma unroll
        for (int s = 0; s < SSEED; ++s)
            acc += a_db[s] * bf2f((unsigned int)dbf_h[(size_t)srow[s] * DIM + t]);
        du[t] = (len > 0) ? acc : 0.f;
    } else {
        int d = t - DIM;
        float acc = 0.f;
#pragma unroll
        for (int s = 0; s < LCON; ++s)
            acc += a_con[s] * bf2f((unsigned int)conf_h[(size_t)crow[s] * DIM + d]);
        cu[d] = acc;
    }
    __syncthreads();
    // fusion (WuT/WiT transposed -> coalesced reads across threads)
    if (t < DIM) {
        float u = bu[t];
        for (int k = 0; k < DIM; ++k) u += cu[k] * WuT[k * DIM + t];
        for (int k = 0; k < DIM; ++k) u += du[k] * WuT[(DIM + k) * DIM + t];
        red[t] = u * gw[t];
    }
    __syncthreads();
    for (int s2 = 64; s2 > 0; s2 >>= 1) {
        if (t < s2) red[t] += red[t + s2];
        __syncthreads();
    }
    if (t < DIM) {
        float gate = 1.f / (1.f + __expf(-(red[0] + gb[0])));
        uemb_h[b * DIM + t] = f2bf(gate * du[t] + (1.f - gate) * cu[t]);
        float ce = bi[t];
        for (int k = 0; k < DIM; ++k) ce += cu[k] * WiT[k * DIM + t];
        cone_h[b * DIM + t] = f2bf(ce);
    }
    if (t == 0) maskv[b] = (len > 0) ? 1.f : 0.f;
}

// ============================ dispatch 7: fused scoring GEMMs (MFMA) + CE/ssq partials
__global__ __launch_bounds__(256) void score_mfma(const unsigned short* __restrict__ dbf_h,
                                                  const unsigned short* __restrict__ uemb_h,
                                                  const unsigned short* __restrict__ cone_h,
                                                  const float* __restrict__ en_b,
                                                  const float* __restrict__ info_b,
                                                  const float* __restrict__ db_vec,
                                                  float* __restrict__ escore,
                                                  float* __restrict__ partM,
                                                  float* __restrict__ partS,
                                                  float* __restrict__ partQ) {
    int wave = threadIdx.x >> 6, lane = threadIdx.x & 63;
    int nt = blockIdx.x * 4 + wave;
    if (nt >= NTILE) return;
    int b0 = blockIdx.y * 32;
    int n0 = nt * 32;
    int am = lane & 31, ak = (lane >> 5) * 8;
    int nb = n0 + am;
    bool bvalid = nb < N_ENT;
    const unsigned short* Au = uemb_h + (size_t)(b0 + am) * DIM + ak;
    const unsigned short* Ac = cone_h + (size_t)(b0 + am) * DIM + ak;
    const unsigned short* Bp = dbf_h + (size_t)nb * DIM + ak;
    facc16 accE, accD;
#pragma unroll
    for (int r = 0; r < 16; ++r) { accE[r] = 0.f; accD[r] = 0.f; }
#pragma unroll
    for (int s = 0; s < 8; ++s) {
        bfrag8 au = *(const bfrag8*)(Au + s * 16);
        bfrag8 ac = *(const bfrag8*)(Ac + s * 16);
        bfrag8 bb;
#pragma unroll
        for (int j = 0; j < 8; ++j) bb[j] = 0;
        if (bvalid) bb = *(const bfrag8*)(Bp + s * 16);
        accE = __builtin_amdgcn_mfma_f32_32x32x16_bf16(au, bb, accE, 0, 0, 0);
        accD = __builtin_amdgcn_mfma_f32_32x32x16_bf16(ac, bb, accD, 0, 0, 0);
    }
    int col = lane & 31;
    int n = n0 + col;
    bool nv = n < N_ENT;
    float enb = nv ? en_b[n] : 0.f;
    float inb = nv ? info_b[n] : 0.f;
    int g4 = (lane >> 5) * 4;
#pragma unroll
    for (int r = 0; r < 16; ++r) {
        int b = b0 + (r & 3) + ((r >> 2) << 3) + g4;
        float e = accE[r] + enb;
        if (nv) __builtin_nontemporal_store(e, &escore[(size_t)b * N_ENT + n]);
        float ev = nv ? e : -1e30f;
        float mx = ev;
#pragma unroll
        for (int off = 16; off >= 1; off >>= 1) mx = fmaxf(mx, __shfl_xor(mx, off, 64));
        float ex = nv ? __expf(e - mx) : 0.f;
        float sm = ex;
#pragma unroll
        for (int off = 16; off >= 1; off >>= 1) sm += __shfl_xor(sm, off, 64);
        float d = nv ? (accD[r] + inb - db_vec[(size_t)b * N_ENT + n]) : 0.f;
        float q = d * d;
#pragma unroll
        for (int off = 16; off >= 1; off >>= 1) q += __shfl_xor(q, off, 64);
        if (col == 0) {
            partM[(size_t)b * NTILE + nt] = mx;
            partS[(size_t)b * NTILE + nt] = sm;
            partQ[(size_t)b * NTILE + nt] = q;
        }
    }
}

// ============================ dispatch 8: CE finalize + last-block final reduction
__global__ __launch_bounds__(256) void ce_final(const float* __restrict__ partM,
                                                const float* __restrict__ partS,
                                                const float* __restrict__ partQ,
                                                const float* __restrict__ escore,
                                                const int* __restrict__ labels,
                                                const float* __restrict__ rec,
                                                float* __restrict__ rloss,
                                                float* __restrict__ ssqv,
                                                const float* __restrict__ maskv,
                                                float* __restrict__ out,
                                                int* __restrict__ counter) {
    __shared__ float red[256], red2[256];
    __shared__ int lastFlag;
    int b = blockIdx.x, t = threadIdx.x;
    const float* pm = partM + (size_t)b * NTILE;
    const float* ps = partS + (size_t)b * NTILE;
    const float* pq = partQ + (size_t)b * NTILE;
    float mx = -1e30f;
    for (int i = t; i < NTILE; i += 256) mx = fmaxf(mx, pm[i]);
    red[t] = mx;
    __syncthreads();
    for (int s2 = 128; s2 > 0; s2 >>= 1) {
        if (t < s2) red[t] = fmaxf(red[t], red[t + s2]);
        __syncthreads();
    }
    float M = red[0];
    __syncthreads();
    float s = 0.f, q = 0.f;
    for (int i = t; i < NTILE; i += 256) {
        s += ps[i] * __expf(pm[i] - M);
        q += pq[i];
    }
    red[t] = s; red2[t] = q;
    __syncthreads();
    for (int s2 = 128; s2 > 0; s2 >>= 1) {
        if (t < s2) { red[t] += red[t + s2]; red2[t] += red2[t + s2]; }
        __syncthreads();
    }
    if (t == 0) {
        float lse = M + logf(red[0]);
        float ce  = -(escore[(size_t)b * N_ENT + labels[b]] - lse);
        rloss[b]  = ce * rec[b];
        ssqv[b]   = red2[0];
        __threadfence();
        int old = atomicAdd(counter, 1);
        lastFlag = (old == BATCH - 1);
    }
    __syncthreads();
    if (!lastFlag) return;
    __threadfence();
    // ---- final scalar reduction by the last block
    red[t]  = rloss[t];
    red2[t] = ssqv[t] * maskv[t];
    __syncthreads();
    for (int s2 = 128; s2 > 0; s2 >>= 1) {
        if (t < s2) { red[t] += red[t + s2]; red2[t] += red2[t + s2]; }
        __syncthreads();
    }
    if (t == 0) {
        float rec_loss = red[0];
        float info = red2[0] / (float)BATCH;
        out[0] = rec_loss + 0.025f * info;
        out[1 + (size_t)BATCH * N_ENT] = rec_loss;
    }
}

// ============================ launch
extern "C" void kernel_launch(void* const* d_in, const int* in_sizes, int n_in,
                              void* d_out, int out_size, void* d_ws, size_t ws_size,
                              hipStream_t stream) {
    (void)in_sizes; (void)n_in; (void)out_size;
    const int*   concept_mask  = (const int*)d_in[0];
    const int*   seed_pad      = (const int*)d_in[1];
    const int*   seed_lens     = (const int*)d_in[2];
    const int*   db_eidx       = (const int*)d_in[3];
    const int*   db_etype      = (const int*)d_in[4];
    const int*   con_eidx      = (const int*)d_in[5];
    const float* db_vec        = (const float*)d_in[6];
    const int*   labels        = (const int*)d_in[7];
    const float* rec           = (const float*)d_in[8];
    const float* concept_emb   = (const float*)d_in[9];
    const float* basis         = (const float*)d_in[10];
    const float* comp          = (const float*)d_in[11];
    const float* rgcn_root     = (const float*)d_in[12];
    const float* rgcn_bias     = (const float*)d_in[13];
    const float* gcn_w         = (const float*)d_in[14];
    const float* gcn_b         = (const float*)d_in[15];
    const float* attn_a        = (const float*)d_in[16];
    const float* attn_b        = (const float*)d_in[17];
    const float* attn_a_db     = (const float*)d_in[18];
    const float* attn_b_db     = (const float*)d_in[19];
    const float* user_norm_w   = (const float*)d_in[20];
    const float* user_norm_b   = (const float*)d_in[21];
    const float* gate_norm_w   = (const float*)d_in[22];
    const float* gate_norm_b   = (const float*)d_in[23];
    const float* info_con_w    = (const float*)d_in[24];
    const float* info_con_b    = (const float*)d_in[25];
    const float* info_out_db_b = (const float*)d_in[26];
    const float* output_en_b   = (const float*)d_in[27];

    float* ws = (float*)d_ws;
    size_t off = 0;
    auto alloc = [&](size_t n) { float* p = ws + off; off += (n + 255) & ~(size_t)255; return p; };
    float* dinv   = alloc(N_CON);
    float* maskv  = alloc(BATCH);
    float* rls    = alloc(BATCH);
    float* ssqv   = alloc(BATCH);
    float* partM  = alloc((size_t)BATCH * NTILE);
    float* partS  = alloc((size_t)BATCH * NTILE);
    float* partQ  = alloc((size_t)BATCH * NTILE);
    int* cnt_e    = (int*)alloc(N_ENT + N_CON + 64);  // contiguous for one memset (incl. counter)
    int* cnt_c    = cnt_e + N_ENT;
    int* counter  = cnt_e + N_ENT + N_CON;
    int* rowptr_e = (int*)alloc(N_ENT + 1);
    int* rowptr_c = (int*)alloc(N_CON + 1);
    int* ord_db   = (int*)alloc(EDB);
    int* ord_con  = (int*)alloc(ECON);
    int* elist_e  = (int*)alloc(EDB);
    int* elist_c  = (int*)alloc(ECON);
    unsigned short* dbf_h  = (unsigned short*)alloc((size_t)N_ENT * DIM / 2);
    unsigned short* conf_h = (unsigned short*)alloc((size_t)N_CON * DIM / 2 + 128);
    unsigned short* xw_h   = (unsigned short*)alloc((size_t)N_CON * DIM / 2 + 128);
    unsigned short* emb_h  = (unsigned short*)alloc((size_t)N_CON * DIM / 2 + 128);
    unsigned short* Wt_h   = (unsigned short*)alloc(DIM * DIM / 2);
    unsigned short* uemb_h = (unsigned short*)alloc(BATCH * DIM / 2);
    unsigned short* cone_h = (unsigned short*)alloc(BATCH * DIM / 2);
    float* e_db   = alloc(N_ENT);
    float* e_con  = alloc(N_CON);
    unsigned short* At_db_h = (unsigned short*)alloc(DIM * DIM / 2);
    unsigned short* At_c_h  = (unsigned short*)alloc(DIM * DIM / 2);
    float* WuT    = alloc(2 * DIM * DIM);
    float* WiT    = alloc(DIM * DIM);
    size_t w_elems = ((size_t)NREL * N_ENT * DIM) / 2;   // bf16 in float-units
    int use_w = (off + w_elems) * sizeof(float) <= ws_size;
    unsigned short* w_h = (unsigned short*)(ws + off);

    float* out    = (float*)d_out;
    float* escore = out + 1;

    (void)hipMemsetAsync(cnt_e, 0, (N_ENT + N_CON + 64) * sizeof(int), stream);

    prep_kernel<<<NB_PREP, 256, 0, stream>>>(
        db_eidx + EDB, con_eidx + ECON, concept_emb, gcn_w, attn_a_db, attn_a,
        user_norm_w, info_con_w, basis, comp, cnt_e, cnt_c, ord_db, ord_con,
        emb_h, Wt_h, At_db_h, At_c_h, WuT, WiT, w_h, use_w);
    scan2_kernel<<<2 + NB_XW, 1024, 0, stream>>>(cnt_e, cnt_c, rowptr_e, rowptr_c, dinv,
                                                 emb_h, Wt_h, xw_h);
    scatter_kernel<<<NB_HIST, 256, 0, stream>>>(db_eidx, db_etype, con_eidx,
                                                ord_db, ord_con, rowptr_e, rowptr_c,
                                                elist_e, elist_c);
    gathers_kernel<<<NB_RG8 * 2, 256, 0, stream>>>(rowptr_e, elist_e, w_h, rgcn_root, rgcn_bias,
                                                   dbf_h, rowptr_c, elist_c, dinv, xw_h, gcn_b,
                                                   conf_h, use_w);
    if (!use_w) {
        rgcn_gather_basis<<<NB_RG, 256, 0, stream>>>(rowptr_e, elist_e, basis, comp,
                                                     rgcn_root, rgcn_bias, dbf_h);
    }
    escores_kernel<<<NB_EDB * 2, 256, 0, stream>>>(dbf_h, At_db_h, attn_b_db, e_db,
                                                   conf_h, At_c_h, attn_b, e_con);
    attn_fusion_kernel<<<BATCH, 256, 0, stream>>>(dbf_h, conf_h, e_db, e_con,
                                                  seed_pad, seed_lens, concept_mask,
                                                  WuT, user_norm_b, gate_norm_w, gate_norm_b,
                                                  WiT, info_con_b, uemb_h, cone_h, maskv);
    dim3 sg((NTILE + 3) / 4, BATCH / 32);
    score_mfma<<<sg, 256, 0, stream>>>(dbf_h, uemb_h, cone_h, output_en_b, info_out_db_b, db_vec,
                                       escore, partM, partS, partQ);
    ce_final<<<BATCH, 256, 0, stream>>>(partM, partS, partQ, escore, labels, rec, rls, ssqv,
                                        maskv, out, counter);
}